// Round 10
// baseline (361.385 us; speedup 1.0000x reference)
//
#include <hip/hip_runtime.h>
#include <math.h>

// ---------------------------------------------------------------------------
// PixelCNN (5 gated residual blocks) + DMOL logprob.  Round 14:
//   - NEW: k_blk uses mfma_f32_32x32x16_bf16 (8 MFMA/step, +21% matrix-pipe
//     efficiency) with 2-oc-tile x 2-px-tile wave ownership: wave (w5,g) owns
//     a-tile w5 + gate-tile w5 x the 2 px32-tiles of row y0+g.
//     -> LDS B-read traffic HALVED (4 ds_read_b128/step, was 8);
//        weights 2x unique (L2-absorbed); MFMA time 16.2 -> 13.5 us/CU.
//   - aF back to 2-deep (r9's 3-deep regressed); d_out zeroing in k_setup.
//   - kept: bf16 residual stream + bf16 relu-mirror + global_load_lds staging
// ---------------------------------------------------------------------------

using short8  = __attribute__((ext_vector_type(8))) short;
using short4v = __attribute__((ext_vector_type(4))) short;
using f32x4   = __attribute__((ext_vector_type(4))) float;
using f32x16  = __attribute__((ext_vector_type(16))) float;

static constexpr float L2E = 1.44269504088896f;   // log2(e)
static constexpr float LN2 = 0.69314718055995f;   // ln(2)

__device__ __forceinline__ float fexp2(float x) { return __builtin_amdgcn_exp2f(x); }
__device__ __forceinline__ float flog2(float x) { return __builtin_amdgcn_logf(x); }
__device__ __forceinline__ float frcp(float x)  { return __builtin_amdgcn_rcpf(x); }
__device__ __forceinline__ float fexp(float x)  { return fexp2(x * L2E); }
__device__ __forceinline__ float flog(float x)  { return flog2(x) * LN2; }
__device__ __forceinline__ float fsigmoid(float x) { return frcp(1.f + fexp2(-x * L2E)); }
__device__ __forceinline__ float ftanh(float x)    { return 1.f - 2.f * frcp(1.f + fexp2(x * (2.f * L2E))); }
__device__ __forceinline__ float fsoftplus(float z) {
    float e = fexp2(-fabsf(z) * L2E);
    return fmaxf(z, 0.f) + flog2(1.f + e) * LN2;
}

// pack two fp32 -> packed bf16 pair (a in low, b in high)
__device__ __forceinline__ unsigned pk_bf16(float a, float b) {
    union { float f; unsigned u; } ua, ub; ua.f = a; ub.f = b;
    return __builtin_amdgcn_perm(ub.u + 0x7fffu, ua.u + 0x7fffu, 0x07060302u);
}

__device__ __forceinline__ short f2bf(float f) {
    union { float f; unsigned u; } v; v.f = f;
    unsigned r = (v.u + 0x7fffu + ((v.u >> 16) & 1u)) >> 16;
    return (short)r;
}

__device__ __forceinline__ float bf2f(short s) {
    union { float f; unsigned u; } v;
    v.u = ((unsigned)(unsigned short)s) << 16;
    return v.f;
}

// async global->LDS DMA, 16B per lane; lds ptr must be wave-uniform
__device__ __forceinline__ void gload_lds16(const void* g, void* l) {
    __builtin_amdgcn_global_load_lds(
        (const __attribute__((address_space(1))) unsigned int*)g,
        (__attribute__((address_space(3))) unsigned int*)l, 16, 0, 0);
}

// workspace layout (bytes), 16B-aligned
static constexpr size_t X_OFF    = 0;             // 16*3*4096*4    = 786432
static constexpr size_t WINP_OFF = 786432;        // 3*160*32*2     = 30720
static constexpr size_t W1P_OFF  = 817152;        // 5*160*32*2     = 51200
static constexpr size_t W2P_OFF  = 868352;        // 5*160*32*2     = 51200
static constexpr size_t WPB_OFF  = 919552;        // 5*25*320*32*2  = 2560000
// bf16 residual stream h: [b][y][x][160], 16*4096*160*2 = 20971520 each
static constexpr size_t HRA_OFF  = 3479552;
static constexpr size_t HRB_OFF  = 24451072;
// bf16 relu-mirror: [b][row 0..64][x 0..65][168], row0 & x in {0,65} are zeros
// 16*65*66*168*2 = 23063040 B (+8192 slack for unconditional DMA over-read)
static constexpr size_t MA_OFF   = 45422592;
static constexpr size_t MB_OFF   = 68493824;      // end ~91.6 MB

static constexpr int MROWP = 66 * 168;            // mirror row pitch (shorts) = 11088
static constexpr int SLOT  = 11264;               // staging slot pitch (shorts) = 22528 B

// ---------------------------------------------------------------------------
// k_setup: all preprocessing in ONE launch (+ d_out zeroing).
// ---------------------------------------------------------------------------
__global__ void k_setup(const float* __restrict__ s,
                        const float* __restrict__ w_in,
                        const float* __restrict__ w_blk,
                        const float* __restrict__ w_out1,
                        const float* __restrict__ w_out2,
                        float* __restrict__ X,
                        short* __restrict__ WINP,
                        short* __restrict__ WPB,
                        short* __restrict__ W1P,
                        short* __restrict__ W2P,
                        short* __restrict__ MA,
                        short* __restrict__ MB,
                        float* __restrict__ out, int outn) {
    int bid = blockIdx.x;
    int t = threadIdx.x;
    if (bid < 768) {                       // ---- prep X (+ out zero)
        if (bid == 0 && t < outn) out[t] = 0.f;
        int i = bid * 256 + t;
        if (i < 16 * 3 * 4096) X[i] = 2.f * s[i] - 1.f;
    } else if (bid < 1278) {               // ---- mirror border zero
        int idx = (bid - 768) * 256 + t;
        if (idx >= 2 * 16 * 194 * 21) return;
        int ch   = idx % 21;
        int cell = (idx / 21) % 194;
        int b    = (idx / (21 * 194)) % 16;
        short* M = (idx >= 16 * 194 * 21) ? MB : MA;
        int row, x;
        if (cell < 66) { row = 0; x = cell; }
        else { row = 1 + (cell - 66) / 2; x = ((cell - 66) & 1) ? 65 : 0; }
        short8 z = {};
        *(short8*)&M[((size_t)b * 65 + row) * MROWP + (size_t)x * 168 + ch * 8] = z;
    } else if (bid < 2278) {               // ---- w_blk transform
        int idx = (bid - 1278) * 256 + t;
        if (idx >= 5 * 320 * 160) return;
        int ic = idx % 160;
        int oc = (idx / 160) % 320;
        int i  = idx / (160 * 320);
        const float* p = w_blk + (size_t)idx * 9;
        float t9[9];
        #pragma unroll
        for (int j = 0; j < 9; ++j) t9[j] = p[j];
        const int ky[5] = {0,0,0,1,1}, kx[5] = {0,1,2,0,1};
        #pragma unroll
        for (int tap = 0; tap < 5; ++tap)
            WPB[(((size_t)i * 25 + tap * 5 + (ic >> 5)) * 320 + oc) * 32 + (ic & 31)] =
                f2bf(t9[ky[tap] * 3 + kx[tap]]);
    } else if (bid < 2338) {               // ---- w_in transform
        int idx = (bid - 2278) * 256 + t;
        if (idx >= 3 * 160 * 32) return;
        int icl = idx & 31;
        int oc  = (idx >> 5) % 160;
        int kc  = idx / 5120;
        int k = kc * 32 + icl;
        short v = 0;
        if (k < 72) {
            int tap = k / 3, ic = k % 3;
            int ky = (tap < 21) ? tap / 7 : 3;
            int kx = (tap < 21) ? tap % 7 : tap - 21;
            v = f2bf(w_in[((oc * 3 + ic) * 7 + ky) * 7 + kx]);
        }
        WINP[idx] = v;
    } else if (bid < 2438) {               // ---- w_out1 transform
        int idx = (bid - 2338) * 256 + t;
        if (idx >= 5 * 160 * 32) return;
        int icl = idx & 31;
        int oc  = (idx >> 5) % 160;
        int kc  = idx / 5120;
        W1P[idx] = f2bf(w_out1[oc * 160 + kc * 32 + icl]);
    } else {                               // ---- w_out2 transform
        int idx = (bid - 2438) * 256 + t;
        if (idx >= 5 * 160 * 32) return;
        int icl = idx & 31;
        int oc  = (idx >> 5) % 160;
        int kc  = idx / 5120;
        W2P[idx] = (oc < 100) ? f2bf(w_out2[oc * 160 + kc * 32 + icl]) : (short)0;
    }
}

// masked 7x7 input conv, MFMA. grid (64,16) = (y,b), block 320 (5 waves).
// Writes h bf16 stream + bf16 relu mirror.
__global__ __launch_bounds__(320) void k_convin(const float* __restrict__ X,
                                                const short* __restrict__ WINP,
                                                short* __restrict__ hrout,
                                                short* __restrict__ Mout) {
    __shared__ float xls[3 * 4 * 72];   // [ic][r=ky][col], col = xg+3 (0..69)
    __shared__ short Bls[64 * 104];     // [px][k pad104]
    int y = blockIdx.x, b = blockIdx.y;
    int t = threadIdx.x;
    for (int i = t; i < 840; i += 320) {
        int col = i % 70; int r = (i / 70) % 4; int ic = i / 280;
        int xg = col - 3, yg = y + r - 3;
        float v = 0.f;
        if (xg >= 0 && xg < 64 && yg >= 0)
            v = X[((size_t)(b * 3 + ic) * 64 + yg) * 64 + xg];
        xls[(ic * 4 + r) * 72 + col] = v;
    }
    __syncthreads();
    for (int i = t; i < 6144; i += 320) {
        int k = i % 96; int px = i / 96;
        short v = 0;
        if (k < 72) {
            int tap = k / 3, ic = k % 3;
            int ky = (tap < 21) ? tap / 7 : 3;
            int kx = (tap < 21) ? tap % 7 : tap - 21;
            v = f2bf(xls[(ic * 4 + ky) * 72 + px + kx]);
        }
        Bls[px * 104 + k] = v;
    }
    __syncthreads();
    int lane = t & 63, wv = t >> 6;
    int lx = lane & 15, q = lane >> 4;
    f32x4 acc[2][4] = {};
    const short* wl = WINP + lx * 32 + q * 8;
    #pragma unroll
    for (int kc = 0; kc < 3; ++kc) {
        short8 aF[2], bF[4];
        aF[0] = *(const short8*)(wl + (kc * 160 + 32 * wv) * 32);
        aF[1] = *(const short8*)(wl + (kc * 160 + 32 * wv + 16) * 32);
        #pragma unroll
        for (int nt = 0; nt < 4; ++nt)
            bF[nt] = *(const short8*)&Bls[(nt * 16 + lx) * 104 + kc * 32 + q * 8];
        #pragma unroll
        for (int mt = 0; mt < 2; ++mt)
            #pragma unroll
            for (int nt = 0; nt < 4; ++nt)
                acc[mt][nt] = __builtin_amdgcn_mfma_f32_16x16x32_bf16(
                    aF[mt], bF[nt], acc[mt][nt], 0, 0, 0);
    }
    size_t rowbase = ((size_t)(b * 64 + y)) * 64 * 160;
    short* mrow = Mout + ((size_t)b * 65 + y + 1) * MROWP;
    #pragma unroll
    for (int mt = 0; mt < 2; ++mt) {
        int c0 = 32 * wv + mt * 16 + q * 4;
        #pragma unroll
        for (int nt = 0; nt < 4; ++nt) {
            int px = nt * 16 + lx;
            float4 o;
            o.x = acc[mt][nt][0]; o.y = acc[mt][nt][1];
            o.z = acc[mt][nt][2]; o.w = acc[mt][nt][3];
            union { short4v s; unsigned u[2]; } hv, mv;
            hv.u[0] = pk_bf16(o.x, o.y);
            hv.u[1] = pk_bf16(o.z, o.w);
            mv.u[0] = pk_bf16(fmaxf(o.x, 0.f), fmaxf(o.y, 0.f));
            mv.u[1] = pk_bf16(fmaxf(o.z, 0.f), fmaxf(o.w, 0.f));
            *(short4v*)&hrout[rowbase + (size_t)px * 160 + c0] = hv.s;
            *(short4v*)&mrow[(size_t)(px + 1) * 168 + c0] = mv.s;
        }
    }
}

// MFMA gated block conv, 32x32x16. grid (32,16) = (y-pair,b), block 640
// (10 waves). Wave (w5,g): a-oc tile 32*w5, gate tile 160+32*w5, px-tiles
// {0,1} of row y0+g. 4 ds_read_b128 + 4 weight loads + 8 MFMA per K=32 step.
__global__ __launch_bounds__(640, 3) void k_blk(const short* __restrict__ hin,
                                                const short* __restrict__ Min,
                                                short* __restrict__ hout,
                                                short* __restrict__ Mout,
                                                const short* __restrict__ wP,
                                                int writeH) {
    __shared__ short in_s[3 * SLOT];   // 3 x 22528 B = 67584 B
    int b = blockIdx.y;
    int y0 = blockIdx.x * 2;
    int t = threadIdx.x;
    int w = t >> 6;               // 0..9
    int lane = t & 63;
    int g  = (w >= 5) ? 1 : 0;    // row group
    int w5 = w - 5 * g;           // oc32-tile index 0..4
    int c31 = lane & 31;          // 32-col (px or oc row)
    int q2  = lane >> 5;          // k-subgroup (0..1)

    // stage mirror rows y0..y0+2 into slots 0..2 (22 chunks x 1024 B per slot)
    #pragma unroll
    for (int m = 0; m < 3; ++m) {
        const short* src = Min + ((size_t)b * 65 + y0 + m) * MROWP;
        #pragma unroll
        for (int k = 0; k < 3; ++k) {
            int ch = k * 10 + w;
            if (ch < 22)
                gload_lds16(src + (size_t)(ch * 64 + lane) * 8, &in_s[m * SLOT + ch * 512]);
        }
    }

    f32x16 acc[4] = {};   // [oct*2+pt]: oct 0=a, 1=gate; pt = px-tile
    // per-lane weight base: oc row = c31, k sub = q2*8
    const short* wl = wP + c31 * 32 + q2 * 8;
    const int aoff = (32 * w5) * 32;          // a-tile   base (shorts)
    const int goff = (160 + 32 * w5) * 32;    // gate-tile base
    const int dxs[5] = {-1, 0, 1, -1, 0};
    const int rws[5] = {0, 0, 0, 1, 1};

    short8 aF[2][4], bF[2][4];   // aF[buf][oct*2+h], bF[buf][pt*2+h]
    // 2-deep weight prologue (steps 0,1)
    #pragma unroll
    for (int p = 0; p < 2; ++p) {
        const short* wk = wl + p * 10240;
        aF[p][0] = *(const short8*)(wk + aoff);
        aF[p][1] = *(const short8*)(wk + aoff + 16);
        aF[p][2] = *(const short8*)(wk + goff);
        aF[p][3] = *(const short8*)(wk + goff + 16);
    }
    __syncthreads();   // staging DMA complete (weights also drained here)

    // B-fragments for step 0 (tap0: row g, dx=-1 -> x = pt*32 + c31)
    {
        const short* s0 = &in_s[g * SLOT];
        #pragma unroll
        for (int pt = 0; pt < 2; ++pt)
            #pragma unroll
            for (int h = 0; h < 2; ++h)
                bF[0][pt * 2 + h] =
                    *(const short8*)&s0[(pt * 32 + c31) * 168 + h * 16 + q2 * 8];
    }
    #pragma unroll
    for (int kk = 0; kk < 25; ++kk) {
        // 1-ahead B prefetch (LDS): 4 fragments (2 px-tiles x 2 k-halves)
        if (kk < 24) {
            int kn = kk + 1, tap = kn / 5, k5 = kn % 5;
            const short* sb = &in_s[(g + rws[tap]) * SLOT];
            int xb = (1 + dxs[tap]) * 168 + k5 * 32 + q2 * 8;
            #pragma unroll
            for (int pt = 0; pt < 2; ++pt)
                #pragma unroll
                for (int h = 0; h < 2; ++h)
                    bF[kn & 1][pt * 2 + h] =
                        *(const short8*)&sb[xb + (pt * 32 + c31) * 168 + h * 16];
        }
        __builtin_amdgcn_s_setprio(1);
        #pragma unroll
        for (int oct = 0; oct < 2; ++oct)
            #pragma unroll
            for (int pt = 0; pt < 2; ++pt)
                #pragma unroll
                for (int h = 0; h < 2; ++h)
                    acc[oct * 2 + pt] = __builtin_amdgcn_mfma_f32_32x32x16_bf16(
                        aF[kk & 1][oct * 2 + h], bF[kk & 1][pt * 2 + h],
                        acc[oct * 2 + pt], 0, 0, 0);
        __builtin_amdgcn_s_setprio(0);
        // 2-ahead weight refill into the buffer just consumed
        if (kk + 2 < 25) {
            const short* wk = wl + (kk + 2) * 10240;
            aF[kk & 1][0] = *(const short8*)(wk + aoff);
            aF[kk & 1][1] = *(const short8*)(wk + aoff + 16);
            aF[kk & 1][2] = *(const short8*)(wk + goff);
            aF[kk & 1][3] = *(const short8*)(wk + goff + 16);
        }
    }
    // epilogue: gating + residual rmw + bf16 relu-mirror write.
    // C/D 32x32 map: col = c31 (px), row = (reg&3) + 8*(reg>>2) + 4*q2 (oc).
    int y = y0 + g;
    size_t rowbase = ((size_t)(b * 64 + y)) * 64 * 160;
    short* mrow = Mout + ((size_t)b * 65 + y + 1) * MROWP;
    #pragma unroll
    for (int pt = 0; pt < 2; ++pt) {
        int px = pt * 32 + c31;
        #pragma unroll
        for (int rq = 0; rq < 4; ++rq) {
            int oc = 32 * w5 + 8 * rq + 4 * q2;
            size_t off = rowbase + (size_t)px * 160 + oc;
            short4v hp = *(const short4v*)&hin[off];
            int r0 = rq * 4;
            float4 o;
            o.x = bf2f(hp.x) + ftanh(acc[pt][r0+0]) * fsigmoid(acc[2+pt][r0+0]);
            o.y = bf2f(hp.y) + ftanh(acc[pt][r0+1]) * fsigmoid(acc[2+pt][r0+1]);
            o.z = bf2f(hp.z) + ftanh(acc[pt][r0+2]) * fsigmoid(acc[2+pt][r0+2]);
            o.w = bf2f(hp.w) + ftanh(acc[pt][r0+3]) * fsigmoid(acc[2+pt][r0+3]);
            union { short4v s; unsigned u[2]; } hv, mv;
            hv.u[0] = pk_bf16(o.x, o.y);
            hv.u[1] = pk_bf16(o.z, o.w);
            mv.u[0] = pk_bf16(fmaxf(o.x, 0.f), fmaxf(o.y, 0.f));
            mv.u[1] = pk_bf16(fmaxf(o.z, 0.f), fmaxf(o.w, 0.f));
            if (writeH) *(short4v*)&hout[off] = hv.s;
            *(short4v*)&mrow[(size_t)(px + 1) * 168 + oc] = mv.s;
        }
    }
}

// fused head: (mirror already holds relu(h) bf16) -> conv1x1(W1) -> relu ->
// conv1x1(W2) -> DMOL -> atomicAdd.  grid (64,16) = (y,b), block 320 (5 waves).
__global__ __launch_bounds__(320) void k_head(const short* __restrict__ Min,
                                              const short* __restrict__ W1P,
                                              const short* __restrict__ W2P,
                                              const float* __restrict__ X,
                                              float* __restrict__ out) {
    __shared__ __align__(16) char arenaA[29696]; // hls(21504) then Pls(26624)+lpls(3072)
    __shared__ short h2ls[64 * 168];             // 21504 B
    short* hls = (short*)arenaA;                 // [px][ic pad168] bf16 relu(h)
    float* Pls = (float*)arenaA;                 // [px][c pad104] fp32 params
    float* lpls = (float*)(arenaA + 26624);      // [px][m pad12]
    int y = blockIdx.x, b = blockIdx.y;
    int t = threadIdx.x;
    int wv = t >> 6;
    // stage relu(h) bf16 straight from mirror (x=1..64 of mirror row y+1)
    const short* src = Min + ((size_t)b * 65 + y + 1) * MROWP + 168;
    #pragma unroll
    for (int k = 0; k < 5; ++k)
        gload_lds16(src + ((size_t)k * 320 + t) * 8, &hls[(k * 320 + wv * 64) * 8]);
    __syncthreads();
    int lane = t & 63;
    int lx = lane & 15, q = lane >> 4;
    // GEMM1: h2 = relu(W1 * relu(h))
    {
        f32x4 acc[2][4] = {};
        const short* wl = W1P + lx * 32 + q * 8;
        #pragma unroll
        for (int kc = 0; kc < 5; ++kc) {
            short8 aF[2], bF[4];
            aF[0] = *(const short8*)(wl + (kc * 160 + 32 * wv) * 32);
            aF[1] = *(const short8*)(wl + (kc * 160 + 32 * wv + 16) * 32);
            #pragma unroll
            for (int nt = 0; nt < 4; ++nt)
                bF[nt] = *(const short8*)&hls[(nt * 16 + lx) * 168 + kc * 32 + q * 8];
            #pragma unroll
            for (int mt = 0; mt < 2; ++mt)
                #pragma unroll
                for (int nt = 0; nt < 4; ++nt)
                    acc[mt][nt] = __builtin_amdgcn_mfma_f32_16x16x32_bf16(
                        aF[mt], bF[nt], acc[mt][nt], 0, 0, 0);
        }
        #pragma unroll
        for (int mt = 0; mt < 2; ++mt) {
            int c0 = 32 * wv + mt * 16 + q * 4;
            #pragma unroll
            for (int nt = 0; nt < 4; ++nt) {
                int px = nt * 16 + lx;
                union { short4v s; unsigned u[2]; } sv;
                sv.u[0] = pk_bf16(fmaxf(acc[mt][nt][0], 0.f), fmaxf(acc[mt][nt][1], 0.f));
                sv.u[1] = pk_bf16(fmaxf(acc[mt][nt][2], 0.f), fmaxf(acc[mt][nt][3], 0.f));
                *(short4v*)&h2ls[px * 168 + c0] = sv.s;
            }
        }
    }
    __syncthreads();
    // GEMM2: params = W2 * h2   (oc padded to 160; only c<100 stored)
    {
        f32x4 acc[2][4] = {};
        const short* wl = W2P + lx * 32 + q * 8;
        #pragma unroll
        for (int kc = 0; kc < 5; ++kc) {
            short8 aF[2], bF[4];
            aF[0] = *(const short8*)(wl + (kc * 160 + 32 * wv) * 32);
            aF[1] = *(const short8*)(wl + (kc * 160 + 32 * wv + 16) * 32);
            #pragma unroll
            for (int nt = 0; nt < 4; ++nt)
                bF[nt] = *(const short8*)&h2ls[(nt * 16 + lx) * 168 + kc * 32 + q * 8];
            #pragma unroll
            for (int mt = 0; mt < 2; ++mt)
                #pragma unroll
                for (int nt = 0; nt < 4; ++nt)
                    acc[mt][nt] = __builtin_amdgcn_mfma_f32_16x16x32_bf16(
                        aF[mt], bF[nt], acc[mt][nt], 0, 0, 0);
        }
        #pragma unroll
        for (int mt = 0; mt < 2; ++mt) {
            int c0 = 32 * wv + mt * 16 + q * 4;
            if (c0 < 100) {
                #pragma unroll
                for (int nt = 0; nt < 4; ++nt) {
                    int px = nt * 16 + lx;
                    float4 o;
                    o.x = acc[mt][nt][0]; o.y = acc[mt][nt][1];
                    o.z = acc[mt][nt][2]; o.w = acc[mt][nt][3];
                    *(float4*)&Pls[px * 104 + c0] = o;
                }
            }
        }
    }
    __syncthreads();
    // DMOL: 640 (px, mixture) tasks over 320 threads
    const float LOG127P5 = 4.8481163504f;   // ln(127.5)
    #pragma unroll
    for (int it = 0; it < 2; ++it) {
        int tk = t + it * 320;
        int px = tk & 63, m = tk >> 6;
        const float* pp = &Pls[px * 104];
        float xs[3];
        #pragma unroll
        for (int c = 0; c < 3; ++c)
            xs[c] = X[((size_t)(b * 3 + c)) * 4096 + (size_t)y * 64 + px];
        float mx = pp[0];
        #pragma unroll
        for (int j = 1; j < 10; ++j) mx = fmaxf(mx, pp[j]);
        float se = 0.f;
        #pragma unroll
        for (int j = 0; j < 10; ++j) se += fexp(pp[j] - mx);
        float lse = mx + flog(se);
        float sum = pp[m] - lse;
        float mean0 = pp[10 + m];
        float mean1 = pp[40 + m];
        float mean2 = pp[70 + m];
        float ls0 = fmaxf(pp[20 + m], -7.f);
        float ls1 = fmaxf(pp[50 + m], -7.f);
        float ls2 = fmaxf(pp[80 + m], -7.f);
        float c0 = ftanh(pp[30 + m]);
        float c1 = ftanh(pp[60 + m]);
        float c2 = ftanh(pp[90 + m]);
        float mu[3], lsv[3];
        mu[0] = mean0;
        mu[1] = mean1 + c0 * xs[0];
        mu[2] = mean2 + c1 * xs[0] + c2 * xs[1];
        lsv[0] = ls0; lsv[1] = ls1; lsv[2] = ls2;
        #pragma unroll
        for (int ci = 0; ci < 3; ++ci) {
            float cent = xs[ci] - mu[ci];
            float inv = fexp(-lsv[ci]);
            float plus_in = inv * (cent + 1.f / 255.f);
            float min_in = inv * (cent - 1.f / 255.f);
            float cdf_delta = fsigmoid(plus_in) - fsigmoid(min_in);
            float log_cdf_plus = plus_in - fsoftplus(plus_in);
            float log_om_cdf = -fsoftplus(min_in);
            float mid = inv * cent;
            float log_pdf_mid = mid - lsv[ci] - 2.f * fsoftplus(mid);
            float lpi = (cdf_delta > 1e-5f) ? flog(fmaxf(cdf_delta, 1e-12f))
                                            : (log_pdf_mid - LOG127P5);
            float lpc = (xs[ci] < -0.999f) ? log_cdf_plus
                       : ((xs[ci] > 0.999f) ? log_om_cdf : lpi);
            sum += lpc;
        }
        lpls[px * 12 + m] = sum;
    }
    __syncthreads();
    if (t < 64) {
        int px = t;
        float mx2 = lpls[px * 12];
        #pragma unroll
        for (int m = 1; m < 10; ++m) mx2 = fmaxf(mx2, lpls[px * 12 + m]);
        float se2 = 0.f;
        #pragma unroll
        for (int m = 0; m < 10; ++m) se2 += fexp(lpls[px * 12 + m] - mx2);
        float lp = mx2 + flog(se2);
        #pragma unroll
        for (int off = 32; off > 0; off >>= 1) lp += __shfl_down(lp, off, 64);
        if (t == 0) atomicAdd(&out[b], lp);
    }
}

extern "C" void kernel_launch(void* const* d_in, const int* in_sizes, int n_in,
                              void* d_out, int out_size, void* d_ws, size_t ws_size,
                              hipStream_t stream) {
    const float* samples = (const float*)d_in[0];
    const float* w_in    = (const float*)d_in[1];
    const float* w_blk   = (const float*)d_in[2];
    const float* w_out1  = (const float*)d_in[3];
    const float* w_out2  = (const float*)d_in[4];
    char* ws = (char*)d_ws;
    float* X    = (float*)(ws + X_OFF);
    short* WINP = (short*)(ws + WINP_OFF);
    short* W1P  = (short*)(ws + W1P_OFF);
    short* W2P  = (short*)(ws + W2P_OFF);
    short* WPB  = (short*)(ws + WPB_OFF);
    short* HRA  = (short*)(ws + HRA_OFF);
    short* HRB  = (short*)(ws + HRB_OFF);
    short* MA   = (short*)(ws + MA_OFF);
    short* MB   = (short*)(ws + MB_OFF);
    float* fout = (float*)d_out;

    k_setup<<<2538, 256, 0, stream>>>(samples, w_in, w_blk, w_out1, w_out2,
                                      X, WINP, WPB, W1P, W2P, MA, MB,
                                      fout, out_size);

    k_convin<<<dim3(64, 16), 320, 0, stream>>>(X, WINP, HRA, MA);

    short* a = HRA; short* bq = HRB;
    short* ma = MA; short* mb = MB;
    for (int i = 0; i < 5; i++) {
        k_blk<<<dim3(32, 16), 640, 0, stream>>>(a, ma, bq, mb,
                                                WPB + (size_t)i * 25 * 320 * 32,
                                                (i < 4) ? 1 : 0);
        short* tf = a; a = bq; bq = tf;
        short* tm = ma; ma = mb; mb = tm;
    }
    // final h mirror is in ma (= MB after 5 swaps)
    k_head<<<dim3(64, 16), 320, 0, stream>>>(ma, W1P, W2P, X, fout);
}

// Round 11
// 336.602 us; speedup vs baseline: 1.0736x; 1.0736x over previous
//
#include <hip/hip_runtime.h>
#include <math.h>

// ---------------------------------------------------------------------------
// PixelCNN (5 gated residual blocks) + DMOL logprob.  Round 15:
//   - k_blk = round-11 structure (best measured 43.7 us/layer: 10 waves,
//     wave w = 16 a-oc + 16 gate-oc x 128 px, 16x16x32, 2-deep aF, 1-ahead bF)
//   - NEW: per-wave k-step ROTATION: wave w runs steps (kk + 12w mod 25),
//     desynchronizing the 10 waves so LDS/MFMA/L2 demand is staggered
//     instead of lockstep-bursted (pipes overlap across waves).
//   - kept: k_setup merge (+d_out zero), writeH skip on last layer,
//     bf16 residual stream + bf16 relu-mirror + global_load_lds staging
// ---------------------------------------------------------------------------

using short8  = __attribute__((ext_vector_type(8))) short;
using short4v = __attribute__((ext_vector_type(4))) short;
using f32x4   = __attribute__((ext_vector_type(4))) float;

static constexpr float L2E = 1.44269504088896f;   // log2(e)
static constexpr float LN2 = 0.69314718055995f;   // ln(2)

__device__ __forceinline__ float fexp2(float x) { return __builtin_amdgcn_exp2f(x); }
__device__ __forceinline__ float flog2(float x) { return __builtin_amdgcn_logf(x); }
__device__ __forceinline__ float frcp(float x)  { return __builtin_amdgcn_rcpf(x); }
__device__ __forceinline__ float fexp(float x)  { return fexp2(x * L2E); }
__device__ __forceinline__ float flog(float x)  { return flog2(x) * LN2; }
__device__ __forceinline__ float fsigmoid(float x) { return frcp(1.f + fexp2(-x * L2E)); }
__device__ __forceinline__ float ftanh(float x)    { return 1.f - 2.f * frcp(1.f + fexp2(x * (2.f * L2E))); }
__device__ __forceinline__ float fsoftplus(float z) {
    float e = fexp2(-fabsf(z) * L2E);
    return fmaxf(z, 0.f) + flog2(1.f + e) * LN2;
}

// pack two fp32 -> packed bf16 pair (a in low, b in high)
__device__ __forceinline__ unsigned pk_bf16(float a, float b) {
    union { float f; unsigned u; } ua, ub; ua.f = a; ub.f = b;
    return __builtin_amdgcn_perm(ub.u + 0x7fffu, ua.u + 0x7fffu, 0x07060302u);
}

__device__ __forceinline__ short f2bf(float f) {
    union { float f; unsigned u; } v; v.f = f;
    unsigned r = (v.u + 0x7fffu + ((v.u >> 16) & 1u)) >> 16;
    return (short)r;
}

__device__ __forceinline__ float bf2f(short s) {
    union { float f; unsigned u; } v;
    v.u = ((unsigned)(unsigned short)s) << 16;
    return v.f;
}

// async global->LDS DMA, 16B per lane; lds ptr must be wave-uniform
__device__ __forceinline__ void gload_lds16(const void* g, void* l) {
    __builtin_amdgcn_global_load_lds(
        (const __attribute__((address_space(1))) unsigned int*)g,
        (__attribute__((address_space(3))) unsigned int*)l, 16, 0, 0);
}

// workspace layout (bytes), 16B-aligned
static constexpr size_t X_OFF    = 0;             // 16*3*4096*4    = 786432
static constexpr size_t WINP_OFF = 786432;        // 3*160*32*2     = 30720
static constexpr size_t W1P_OFF  = 817152;        // 5*160*32*2     = 51200
static constexpr size_t W2P_OFF  = 868352;        // 5*160*32*2     = 51200
static constexpr size_t WPB_OFF  = 919552;        // 5*25*320*32*2  = 2560000
// bf16 residual stream h: [b][y][x][160], 16*4096*160*2 = 20971520 each
static constexpr size_t HRA_OFF  = 3479552;
static constexpr size_t HRB_OFF  = 24451072;
// bf16 relu-mirror: [b][row 0..64][x 0..65][168], row0 & x in {0,65} are zeros
// 16*65*66*168*2 = 23063040 B (+8192 slack for unconditional DMA over-read)
static constexpr size_t MA_OFF   = 45422592;
static constexpr size_t MB_OFF   = 68493824;      // end ~91.6 MB

static constexpr int MROWP = 66 * 168;            // mirror row pitch (shorts) = 11088
static constexpr int SLOT  = 11264;               // staging slot pitch (shorts) = 22528 B

// ---------------------------------------------------------------------------
// k_setup: all preprocessing in ONE launch (+ d_out zeroing).
// ---------------------------------------------------------------------------
__global__ void k_setup(const float* __restrict__ s,
                        const float* __restrict__ w_in,
                        const float* __restrict__ w_blk,
                        const float* __restrict__ w_out1,
                        const float* __restrict__ w_out2,
                        float* __restrict__ X,
                        short* __restrict__ WINP,
                        short* __restrict__ WPB,
                        short* __restrict__ W1P,
                        short* __restrict__ W2P,
                        short* __restrict__ MA,
                        short* __restrict__ MB,
                        float* __restrict__ out, int outn) {
    int bid = blockIdx.x;
    int t = threadIdx.x;
    if (bid < 768) {                       // ---- prep X (+ out zero)
        if (bid == 0 && t < outn) out[t] = 0.f;
        int i = bid * 256 + t;
        if (i < 16 * 3 * 4096) X[i] = 2.f * s[i] - 1.f;
    } else if (bid < 1278) {               // ---- mirror border zero
        int idx = (bid - 768) * 256 + t;
        if (idx >= 2 * 16 * 194 * 21) return;
        int ch   = idx % 21;
        int cell = (idx / 21) % 194;
        int b    = (idx / (21 * 194)) % 16;
        short* M = (idx >= 16 * 194 * 21) ? MB : MA;
        int row, x;
        if (cell < 66) { row = 0; x = cell; }
        else { row = 1 + (cell - 66) / 2; x = ((cell - 66) & 1) ? 65 : 0; }
        short8 z = {};
        *(short8*)&M[((size_t)b * 65 + row) * MROWP + (size_t)x * 168 + ch * 8] = z;
    } else if (bid < 2278) {               // ---- w_blk transform
        int idx = (bid - 1278) * 256 + t;
        if (idx >= 5 * 320 * 160) return;
        int ic = idx % 160;
        int oc = (idx / 160) % 320;
        int i  = idx / (160 * 320);
        const float* p = w_blk + (size_t)idx * 9;
        float t9[9];
        #pragma unroll
        for (int j = 0; j < 9; ++j) t9[j] = p[j];
        const int ky[5] = {0,0,0,1,1}, kx[5] = {0,1,2,0,1};
        #pragma unroll
        for (int tap = 0; tap < 5; ++tap)
            WPB[(((size_t)i * 25 + tap * 5 + (ic >> 5)) * 320 + oc) * 32 + (ic & 31)] =
                f2bf(t9[ky[tap] * 3 + kx[tap]]);
    } else if (bid < 2338) {               // ---- w_in transform
        int idx = (bid - 2278) * 256 + t;
        if (idx >= 3 * 160 * 32) return;
        int icl = idx & 31;
        int oc  = (idx >> 5) % 160;
        int kc  = idx / 5120;
        int k = kc * 32 + icl;
        short v = 0;
        if (k < 72) {
            int tap = k / 3, ic = k % 3;
            int ky = (tap < 21) ? tap / 7 : 3;
            int kx = (tap < 21) ? tap % 7 : tap - 21;
            v = f2bf(w_in[((oc * 3 + ic) * 7 + ky) * 7 + kx]);
        }
        WINP[idx] = v;
    } else if (bid < 2438) {               // ---- w_out1 transform
        int idx = (bid - 2338) * 256 + t;
        if (idx >= 5 * 160 * 32) return;
        int icl = idx & 31;
        int oc  = (idx >> 5) % 160;
        int kc  = idx / 5120;
        W1P[idx] = f2bf(w_out1[oc * 160 + kc * 32 + icl]);
    } else {                               // ---- w_out2 transform
        int idx = (bid - 2438) * 256 + t;
        if (idx >= 5 * 160 * 32) return;
        int icl = idx & 31;
        int oc  = (idx >> 5) % 160;
        int kc  = idx / 5120;
        W2P[idx] = (oc < 100) ? f2bf(w_out2[oc * 160 + kc * 32 + icl]) : (short)0;
    }
}

// masked 7x7 input conv, MFMA. grid (64,16) = (y,b), block 320 (5 waves).
// Writes h bf16 stream + bf16 relu mirror.
__global__ __launch_bounds__(320) void k_convin(const float* __restrict__ X,
                                                const short* __restrict__ WINP,
                                                short* __restrict__ hrout,
                                                short* __restrict__ Mout) {
    __shared__ float xls[3 * 4 * 72];   // [ic][r=ky][col], col = xg+3 (0..69)
    __shared__ short Bls[64 * 104];     // [px][k pad104]
    int y = blockIdx.x, b = blockIdx.y;
    int t = threadIdx.x;
    for (int i = t; i < 840; i += 320) {
        int col = i % 70; int r = (i / 70) % 4; int ic = i / 280;
        int xg = col - 3, yg = y + r - 3;
        float v = 0.f;
        if (xg >= 0 && xg < 64 && yg >= 0)
            v = X[((size_t)(b * 3 + ic) * 64 + yg) * 64 + xg];
        xls[(ic * 4 + r) * 72 + col] = v;
    }
    __syncthreads();
    for (int i = t; i < 6144; i += 320) {
        int k = i % 96; int px = i / 96;
        short v = 0;
        if (k < 72) {
            int tap = k / 3, ic = k % 3;
            int ky = (tap < 21) ? tap / 7 : 3;
            int kx = (tap < 21) ? tap % 7 : tap - 21;
            v = f2bf(xls[(ic * 4 + ky) * 72 + px + kx]);
        }
        Bls[px * 104 + k] = v;
    }
    __syncthreads();
    int lane = t & 63, wv = t >> 6;
    int lx = lane & 15, q = lane >> 4;
    f32x4 acc[2][4] = {};
    const short* wl = WINP + lx * 32 + q * 8;
    #pragma unroll
    for (int kc = 0; kc < 3; ++kc) {
        short8 aF[2], bF[4];
        aF[0] = *(const short8*)(wl + (kc * 160 + 32 * wv) * 32);
        aF[1] = *(const short8*)(wl + (kc * 160 + 32 * wv + 16) * 32);
        #pragma unroll
        for (int nt = 0; nt < 4; ++nt)
            bF[nt] = *(const short8*)&Bls[(nt * 16 + lx) * 104 + kc * 32 + q * 8];
        #pragma unroll
        for (int mt = 0; mt < 2; ++mt)
            #pragma unroll
            for (int nt = 0; nt < 4; ++nt)
                acc[mt][nt] = __builtin_amdgcn_mfma_f32_16x16x32_bf16(
                    aF[mt], bF[nt], acc[mt][nt], 0, 0, 0);
    }
    size_t rowbase = ((size_t)(b * 64 + y)) * 64 * 160;
    short* mrow = Mout + ((size_t)b * 65 + y + 1) * MROWP;
    #pragma unroll
    for (int mt = 0; mt < 2; ++mt) {
        int c0 = 32 * wv + mt * 16 + q * 4;
        #pragma unroll
        for (int nt = 0; nt < 4; ++nt) {
            int px = nt * 16 + lx;
            float4 o;
            o.x = acc[mt][nt][0]; o.y = acc[mt][nt][1];
            o.z = acc[mt][nt][2]; o.w = acc[mt][nt][3];
            union { short4v s; unsigned u[2]; } hv, mv;
            hv.u[0] = pk_bf16(o.x, o.y);
            hv.u[1] = pk_bf16(o.z, o.w);
            mv.u[0] = pk_bf16(fmaxf(o.x, 0.f), fmaxf(o.y, 0.f));
            mv.u[1] = pk_bf16(fmaxf(o.z, 0.f), fmaxf(o.w, 0.f));
            *(short4v*)&hrout[rowbase + (size_t)px * 160 + c0] = hv.s;
            *(short4v*)&mrow[(size_t)(px + 1) * 168 + c0] = mv.s;
        }
    }
}

// MFMA gated block conv. grid (32,16) = (y-pair,b), block 640 (10 waves).
// Wave w owns a-channels 16w..16w+15 and gate-channels 160+16w.. for ALL
// 128 px (rows y0,y0+1). Weights read once per block, 2-deep register
// pipeline. NEW: per-wave step ROTATION (phase = 12w mod 25) desyncs the
// 10 waves so LDS/MFMA/L2 phases overlap across waves instead of bursting.
__global__ __launch_bounds__(640, 3) void k_blk(const short* __restrict__ hin,
                                                const short* __restrict__ Min,
                                                short* __restrict__ hout,
                                                short* __restrict__ Mout,
                                                const short* __restrict__ wP,
                                                int writeH) {
    __shared__ short in_s[3 * SLOT];   // 3 x 22528 B = 67584 B
    int b = blockIdx.y;
    int y0 = blockIdx.x * 2;
    int t = threadIdx.x;
    int w = t >> 6;               // 0..9 (oc-slice)
    int lane = t & 63;
    int lx = lane & 15, q = lane >> 4;

    // stage mirror rows y0..y0+2 into slots 0..2 (22 chunks x 1024 B per slot)
    #pragma unroll
    for (int m = 0; m < 3; ++m) {
        const short* src = Min + ((size_t)b * 65 + y0 + m) * MROWP;
        #pragma unroll
        for (int k = 0; k < 3; ++k) {
            int ch = k * 10 + w;
            if (ch < 22)
                gload_lds16(src + (size_t)(ch * 64 + lane) * 8, &in_s[m * SLOT + ch * 512]);
        }
    }

    int phase = (w * 12) % 25;    // wave-uniform rotation offset (10 distinct)

    f32x4 acc[2][8] = {};
    const short* wl = wP + lx * 32 + q * 8;
    const int dxs[5] = {-1, 0, 1, -1, 0};
    const int rws[5] = {0, 0, 0, 1, 1};

    short8 aF[2][2], bF[2][8];
    // 2-deep weight prologue for rotated steps phase, phase+1
    #pragma unroll
    for (int p = 0; p < 2; ++p) {
        int rp = phase + p; if (rp >= 25) rp -= 25;
        const short* wk = wl + rp * 10240;
        aF[p][0] = *(const short8*)(wk + (16 * w) * 32);
        aF[p][1] = *(const short8*)(wk + (160 + 16 * w) * 32);
    }
    __syncthreads();   // staging DMA complete (weights also drained here)

    // B-fragments for rotated step 0
    {
        int kn = phase;
        int tap = kn / 5, k5 = kn % 5;
        int base0 = rws[tap] ? SLOT : 0;
        int base1 = rws[tap] ? 2 * SLOT : SLOT;
        int rb = (1 + dxs[tap] + lx) * 168 + q * 8 + k5 * 32;
        #pragma unroll
        for (int nt = 0; nt < 4; ++nt) {
            bF[0][nt]     = *(const short8*)&in_s[base0 + rb + nt * 16 * 168];
            bF[0][nt + 4] = *(const short8*)&in_s[base1 + rb + nt * 16 * 168];
        }
    }
    #pragma unroll
    for (int kk = 0; kk < 25; ++kk) {
        // 1-ahead B prefetch (LDS): 8 fragments (4 px-tiles x 2 rows)
        if (kk < 24) {
            int kn = kk + 1 + phase; if (kn >= 25) kn -= 25;
            int tap = kn / 5, k5 = kn % 5;
            int base0 = rws[tap] ? SLOT : 0;
            int base1 = rws[tap] ? 2 * SLOT : SLOT;
            int rb = (1 + dxs[tap] + lx) * 168 + q * 8 + k5 * 32;
            #pragma unroll
            for (int nt = 0; nt < 4; ++nt) {
                bF[(kk + 1) & 1][nt]     = *(const short8*)&in_s[base0 + rb + nt * 16 * 168];
                bF[(kk + 1) & 1][nt + 4] = *(const short8*)&in_s[base1 + rb + nt * 16 * 168];
            }
        }
        __builtin_amdgcn_s_setprio(1);
        #pragma unroll
        for (int mt = 0; mt < 2; ++mt)
            #pragma unroll
            for (int nt = 0; nt < 8; ++nt)
                acc[mt][nt] = __builtin_amdgcn_mfma_f32_16x16x32_bf16(
                    aF[kk & 1][mt], bF[kk & 1][nt], acc[mt][nt], 0, 0, 0);
        __builtin_amdgcn_s_setprio(0);
        // 2-ahead weight refill into the buffer just consumed
        if (kk + 2 < 25) {
            int kw = kk + 2 + phase; if (kw >= 25) kw -= 25;
            const short* wk = wl + kw * 10240;
            aF[kk & 1][0] = *(const short8*)(wk + (16 * w) * 32);
            aF[kk & 1][1] = *(const short8*)(wk + (160 + 16 * w) * 32);
        }
    }
    // epilogue: gating + residual rmw (bf16 stream) + bf16 relu-mirror write
    int c0 = 16 * w + q * 4;
    #pragma unroll
    for (int r = 0; r < 2; ++r) {
        int y = y0 + r;
        size_t rowbase = ((size_t)(b * 64 + y)) * 64 * 160;
        short* mrow = Mout + ((size_t)b * 65 + y + 1) * MROWP;
        #pragma unroll
        for (int nt = 0; nt < 4; ++nt) {
            int idx = r * 4 + nt;
            int px = nt * 16 + lx;
            size_t off = rowbase + (size_t)px * 160 + c0;
            short4v hp = *(const short4v*)&hin[off];
            float4 o;
            o.x = bf2f(hp.x) + ftanh(acc[0][idx][0]) * fsigmoid(acc[1][idx][0]);
            o.y = bf2f(hp.y) + ftanh(acc[0][idx][1]) * fsigmoid(acc[1][idx][1]);
            o.z = bf2f(hp.z) + ftanh(acc[0][idx][2]) * fsigmoid(acc[1][idx][2]);
            o.w = bf2f(hp.w) + ftanh(acc[0][idx][3]) * fsigmoid(acc[1][idx][3]);
            union { short4v s; unsigned u[2]; } hv, mv;
            hv.u[0] = pk_bf16(o.x, o.y);
            hv.u[1] = pk_bf16(o.z, o.w);
            mv.u[0] = pk_bf16(fmaxf(o.x, 0.f), fmaxf(o.y, 0.f));
            mv.u[1] = pk_bf16(fmaxf(o.z, 0.f), fmaxf(o.w, 0.f));
            if (writeH) *(short4v*)&hout[off] = hv.s;
            *(short4v*)&mrow[(size_t)(px + 1) * 168 + c0] = mv.s;
        }
    }
}

// fused head: (mirror already holds relu(h) bf16) -> conv1x1(W1) -> relu ->
// conv1x1(W2) -> DMOL -> atomicAdd.  grid (64,16) = (y,b), block 320 (5 waves).
__global__ __launch_bounds__(320) void k_head(const short* __restrict__ Min,
                                              const short* __restrict__ W1P,
                                              const short* __restrict__ W2P,
                                              const float* __restrict__ X,
                                              float* __restrict__ out) {
    __shared__ __align__(16) char arenaA[29696]; // hls(21504) then Pls(26624)+lpls(3072)
    __shared__ short h2ls[64 * 168];             // 21504 B
    short* hls = (short*)arenaA;                 // [px][ic pad168] bf16 relu(h)
    float* Pls = (float*)arenaA;                 // [px][c pad104] fp32 params
    float* lpls = (float*)(arenaA + 26624);      // [px][m pad12]
    int y = blockIdx.x, b = blockIdx.y;
    int t = threadIdx.x;
    int wv = t >> 6;
    // stage relu(h) bf16 straight from mirror (x=1..64 of mirror row y+1)
    const short* src = Min + ((size_t)b * 65 + y + 1) * MROWP + 168;
    #pragma unroll
    for (int k = 0; k < 5; ++k)
        gload_lds16(src + ((size_t)k * 320 + t) * 8, &hls[(k * 320 + wv * 64) * 8]);
    __syncthreads();
    int lane = t & 63;
    int lx = lane & 15, q = lane >> 4;
    // GEMM1: h2 = relu(W1 * relu(h))
    {
        f32x4 acc[2][4] = {};
        const short* wl = W1P + lx * 32 + q * 8;
        #pragma unroll
        for (int kc = 0; kc < 5; ++kc) {
            short8 aF[2], bF[4];
            aF[0] = *(const short8*)(wl + (kc * 160 + 32 * wv) * 32);
            aF[1] = *(const short8*)(wl + (kc * 160 + 32 * wv + 16) * 32);
            #pragma unroll
            for (int nt = 0; nt < 4; ++nt)
                bF[nt] = *(const short8*)&hls[(nt * 16 + lx) * 168 + kc * 32 + q * 8];
            #pragma unroll
            for (int mt = 0; mt < 2; ++mt)
                #pragma unroll
                for (int nt = 0; nt < 4; ++nt)
                    acc[mt][nt] = __builtin_amdgcn_mfma_f32_16x16x32_bf16(
                        aF[mt], bF[nt], acc[mt][nt], 0, 0, 0);
        }
        #pragma unroll
        for (int mt = 0; mt < 2; ++mt) {
            int c0 = 32 * wv + mt * 16 + q * 4;
            #pragma unroll
            for (int nt = 0; nt < 4; ++nt) {
                int px = nt * 16 + lx;
                union { short4v s; unsigned u[2]; } sv;
                sv.u[0] = pk_bf16(fmaxf(acc[mt][nt][0], 0.f), fmaxf(acc[mt][nt][1], 0.f));
                sv.u[1] = pk_bf16(fmaxf(acc[mt][nt][2], 0.f), fmaxf(acc[mt][nt][3], 0.f));
                *(short4v*)&h2ls[px * 168 + c0] = sv.s;
            }
        }
    }
    __syncthreads();
    // GEMM2: params = W2 * h2   (oc padded to 160; only c<100 stored)
    {
        f32x4 acc[2][4] = {};
        const short* wl = W2P + lx * 32 + q * 8;
        #pragma unroll
        for (int kc = 0; kc < 5; ++kc) {
            short8 aF[2], bF[4];
            aF[0] = *(const short8*)(wl + (kc * 160 + 32 * wv) * 32);
            aF[1] = *(const short8*)(wl + (kc * 160 + 32 * wv + 16) * 32);
            #pragma unroll
            for (int nt = 0; nt < 4; ++nt)
                bF[nt] = *(const short8*)&h2ls[(nt * 16 + lx) * 168 + kc * 32 + q * 8];
            #pragma unroll
            for (int mt = 0; mt < 2; ++mt)
                #pragma unroll
                for (int nt = 0; nt < 4; ++nt)
                    acc[mt][nt] = __builtin_amdgcn_mfma_f32_16x16x32_bf16(
                        aF[mt], bF[nt], acc[mt][nt], 0, 0, 0);
        }
        #pragma unroll
        for (int mt = 0; mt < 2; ++mt) {
            int c0 = 32 * wv + mt * 16 + q * 4;
            if (c0 < 100) {
                #pragma unroll
                for (int nt = 0; nt < 4; ++nt) {
                    int px = nt * 16 + lx;
                    float4 o;
                    o.x = acc[mt][nt][0]; o.y = acc[mt][nt][1];
                    o.z = acc[mt][nt][2]; o.w = acc[mt][nt][3];
                    *(float4*)&Pls[px * 104 + c0] = o;
                }
            }
        }
    }
    __syncthreads();
    // DMOL: 640 (px, mixture) tasks over 320 threads
    const float LOG127P5 = 4.8481163504f;   // ln(127.5)
    #pragma unroll
    for (int it = 0; it < 2; ++it) {
        int tk = t + it * 320;
        int px = tk & 63, m = tk >> 6;
        const float* pp = &Pls[px * 104];
        float xs[3];
        #pragma unroll
        for (int c = 0; c < 3; ++c)
            xs[c] = X[((size_t)(b * 3 + c)) * 4096 + (size_t)y * 64 + px];
        float mx = pp[0];
        #pragma unroll
        for (int j = 1; j < 10; ++j) mx = fmaxf(mx, pp[j]);
        float se = 0.f;
        #pragma unroll
        for (int j = 0; j < 10; ++j) se += fexp(pp[j] - mx);
        float lse = mx + flog(se);
        float sum = pp[m] - lse;
        float mean0 = pp[10 + m];
        float mean1 = pp[40 + m];
        float mean2 = pp[70 + m];
        float ls0 = fmaxf(pp[20 + m], -7.f);
        float ls1 = fmaxf(pp[50 + m], -7.f);
        float ls2 = fmaxf(pp[80 + m], -7.f);
        float c0 = ftanh(pp[30 + m]);
        float c1 = ftanh(pp[60 + m]);
        float c2 = ftanh(pp[90 + m]);
        float mu[3], lsv[3];
        mu[0] = mean0;
        mu[1] = mean1 + c0 * xs[0];
        mu[2] = mean2 + c1 * xs[0] + c2 * xs[1];
        lsv[0] = ls0; lsv[1] = ls1; lsv[2] = ls2;
        #pragma unroll
        for (int ci = 0; ci < 3; ++ci) {
            float cent = xs[ci] - mu[ci];
            float inv = fexp(-lsv[ci]);
            float plus_in = inv * (cent + 1.f / 255.f);
            float min_in = inv * (cent - 1.f / 255.f);
            float cdf_delta = fsigmoid(plus_in) - fsigmoid(min_in);
            float log_cdf_plus = plus_in - fsoftplus(plus_in);
            float log_om_cdf = -fsoftplus(min_in);
            float mid = inv * cent;
            float log_pdf_mid = mid - lsv[ci] - 2.f * fsoftplus(mid);
            float lpi = (cdf_delta > 1e-5f) ? flog(fmaxf(cdf_delta, 1e-12f))
                                            : (log_pdf_mid - LOG127P5);
            float lpc = (xs[ci] < -0.999f) ? log_cdf_plus
                       : ((xs[ci] > 0.999f) ? log_om_cdf : lpi);
            sum += lpc;
        }
        lpls[px * 12 + m] = sum;
    }
    __syncthreads();
    if (t < 64) {
        int px = t;
        float mx2 = lpls[px * 12];
        #pragma unroll
        for (int m = 1; m < 10; ++m) mx2 = fmaxf(mx2, lpls[px * 12 + m]);
        float se2 = 0.f;
        #pragma unroll
        for (int m = 0; m < 10; ++m) se2 += fexp(lpls[px * 12 + m] - mx2);
        float lp = mx2 + flog(se2);
        #pragma unroll
        for (int off = 32; off > 0; off >>= 1) lp += __shfl_down(lp, off, 64);
        if (t == 0) atomicAdd(&out[b], lp);
    }
}

extern "C" void kernel_launch(void* const* d_in, const int* in_sizes, int n_in,
                              void* d_out, int out_size, void* d_ws, size_t ws_size,
                              hipStream_t stream) {
    const float* samples = (const float*)d_in[0];
    const float* w_in    = (const float*)d_in[1];
    const float* w_blk   = (const float*)d_in[2];
    const float* w_out1  = (const float*)d_in[3];
    const float* w_out2  = (const float*)d_in[4];
    char* ws = (char*)d_ws;
    float* X    = (float*)(ws + X_OFF);
    short* WINP = (short*)(ws + WINP_OFF);
    short* W1P  = (short*)(ws + W1P_OFF);
    short* W2P  = (short*)(ws + W2P_OFF);
    short* WPB  = (short*)(ws + WPB_OFF);
    short* HRA  = (short*)(ws + HRA_OFF);
    short* HRB  = (short*)(ws + HRB_OFF);
    short* MA   = (short*)(ws + MA_OFF);
    short* MB   = (short*)(ws + MB_OFF);
    float* fout = (float*)d_out;

    k_setup<<<2538, 256, 0, stream>>>(samples, w_in, w_blk, w_out1, w_out2,
                                      X, WINP, WPB, W1P, W2P, MA, MB,
                                      fout, out_size);

    k_convin<<<dim3(64, 16), 320, 0, stream>>>(X, WINP, HRA, MA);

    short* a = HRA; short* bq = HRB;
    short* ma = MA; short* mb = MB;
    for (int i = 0; i < 5; i++) {
        k_blk<<<dim3(32, 16), 640, 0, stream>>>(a, ma, bq, mb,
                                                WPB + (size_t)i * 25 * 320 * 32,
                                                (i < 4) ? 1 : 0);
        short* tf = a; a = bq; bq = tf;
        short* tm = ma; ma = mb; mb = tm;
    }
    // final h mirror is in ma (= MB after 5 swaps)
    k_head<<<dim3(64, 16), 320, 0, stream>>>(ma, W1P, W2P, X, fout);
}

// Round 12
// 330.505 us; speedup vs baseline: 1.0934x; 1.0184x over previous
//
#include <hip/hip_runtime.h>
#include <math.h>

// ---------------------------------------------------------------------------
// PixelCNN (5 gated residual blocks) + DMOL logprob.  Round 16:
//   - k_blk = round-11 exact structure (best measured 43.7 us/layer:
//     10 waves, wave w = 16 a-oc + 16 gate-oc x 128 px, 16x16x32,
//     2-deep aF, 1-ahead bF, NO rotation — r15's rotation cost VALU).
//   - NEW: T14 residual prefetch — epilogue hin loads issued BEFORE the
//     staging barrier (drain overlaps DMA + weight prologue).
//   - kept: k_setup merge (+d_out zero), writeH skip on last layer,
//     bf16 residual stream + bf16 relu-mirror + global_load_lds staging
// ---------------------------------------------------------------------------

using short8  = __attribute__((ext_vector_type(8))) short;
using short4v = __attribute__((ext_vector_type(4))) short;
using f32x4   = __attribute__((ext_vector_type(4))) float;

static constexpr float L2E = 1.44269504088896f;   // log2(e)
static constexpr float LN2 = 0.69314718055995f;   // ln(2)

__device__ __forceinline__ float fexp2(float x) { return __builtin_amdgcn_exp2f(x); }
__device__ __forceinline__ float flog2(float x) { return __builtin_amdgcn_logf(x); }
__device__ __forceinline__ float frcp(float x)  { return __builtin_amdgcn_rcpf(x); }
__device__ __forceinline__ float fexp(float x)  { return fexp2(x * L2E); }
__device__ __forceinline__ float flog(float x)  { return flog2(x) * LN2; }
__device__ __forceinline__ float fsigmoid(float x) { return frcp(1.f + fexp2(-x * L2E)); }
__device__ __forceinline__ float ftanh(float x)    { return 1.f - 2.f * frcp(1.f + fexp2(x * (2.f * L2E))); }
__device__ __forceinline__ float fsoftplus(float z) {
    float e = fexp2(-fabsf(z) * L2E);
    return fmaxf(z, 0.f) + flog2(1.f + e) * LN2;
}

// pack two fp32 -> packed bf16 pair (a in low, b in high)
__device__ __forceinline__ unsigned pk_bf16(float a, float b) {
    union { float f; unsigned u; } ua, ub; ua.f = a; ub.f = b;
    return __builtin_amdgcn_perm(ub.u + 0x7fffu, ua.u + 0x7fffu, 0x07060302u);
}

__device__ __forceinline__ short f2bf(float f) {
    union { float f; unsigned u; } v; v.f = f;
    unsigned r = (v.u + 0x7fffu + ((v.u >> 16) & 1u)) >> 16;
    return (short)r;
}

__device__ __forceinline__ float bf2f(short s) {
    union { float f; unsigned u; } v;
    v.u = ((unsigned)(unsigned short)s) << 16;
    return v.f;
}

// async global->LDS DMA, 16B per lane; lds ptr must be wave-uniform
__device__ __forceinline__ void gload_lds16(const void* g, void* l) {
    __builtin_amdgcn_global_load_lds(
        (const __attribute__((address_space(1))) unsigned int*)g,
        (__attribute__((address_space(3))) unsigned int*)l, 16, 0, 0);
}

// workspace layout (bytes), 16B-aligned
static constexpr size_t X_OFF    = 0;             // 16*3*4096*4    = 786432
static constexpr size_t WINP_OFF = 786432;        // 3*160*32*2     = 30720
static constexpr size_t W1P_OFF  = 817152;        // 5*160*32*2     = 51200
static constexpr size_t W2P_OFF  = 868352;        // 5*160*32*2     = 51200
static constexpr size_t WPB_OFF  = 919552;        // 5*25*320*32*2  = 2560000
// bf16 residual stream h: [b][y][x][160], 16*4096*160*2 = 20971520 each
static constexpr size_t HRA_OFF  = 3479552;
static constexpr size_t HRB_OFF  = 24451072;
// bf16 relu-mirror: [b][row 0..64][x 0..65][168], row0 & x in {0,65} are zeros
// 16*65*66*168*2 = 23063040 B (+8192 slack for unconditional DMA over-read)
static constexpr size_t MA_OFF   = 45422592;
static constexpr size_t MB_OFF   = 68493824;      // end ~91.6 MB

static constexpr int MROWP = 66 * 168;            // mirror row pitch (shorts) = 11088
static constexpr int SLOT  = 11264;               // staging slot pitch (shorts) = 22528 B

// ---------------------------------------------------------------------------
// k_setup: all preprocessing in ONE launch (+ d_out zeroing).
// ---------------------------------------------------------------------------
__global__ void k_setup(const float* __restrict__ s,
                        const float* __restrict__ w_in,
                        const float* __restrict__ w_blk,
                        const float* __restrict__ w_out1,
                        const float* __restrict__ w_out2,
                        float* __restrict__ X,
                        short* __restrict__ WINP,
                        short* __restrict__ WPB,
                        short* __restrict__ W1P,
                        short* __restrict__ W2P,
                        short* __restrict__ MA,
                        short* __restrict__ MB,
                        float* __restrict__ out, int outn) {
    int bid = blockIdx.x;
    int t = threadIdx.x;
    if (bid < 768) {                       // ---- prep X (+ out zero)
        if (bid == 0 && t < outn) out[t] = 0.f;
        int i = bid * 256 + t;
        if (i < 16 * 3 * 4096) X[i] = 2.f * s[i] - 1.f;
    } else if (bid < 1278) {               // ---- mirror border zero
        int idx = (bid - 768) * 256 + t;
        if (idx >= 2 * 16 * 194 * 21) return;
        int ch   = idx % 21;
        int cell = (idx / 21) % 194;
        int b    = (idx / (21 * 194)) % 16;
        short* M = (idx >= 16 * 194 * 21) ? MB : MA;
        int row, x;
        if (cell < 66) { row = 0; x = cell; }
        else { row = 1 + (cell - 66) / 2; x = ((cell - 66) & 1) ? 65 : 0; }
        short8 z = {};
        *(short8*)&M[((size_t)b * 65 + row) * MROWP + (size_t)x * 168 + ch * 8] = z;
    } else if (bid < 2278) {               // ---- w_blk transform
        int idx = (bid - 1278) * 256 + t;
        if (idx >= 5 * 320 * 160) return;
        int ic = idx % 160;
        int oc = (idx / 160) % 320;
        int i  = idx / (160 * 320);
        const float* p = w_blk + (size_t)idx * 9;
        float t9[9];
        #pragma unroll
        for (int j = 0; j < 9; ++j) t9[j] = p[j];
        const int ky[5] = {0,0,0,1,1}, kx[5] = {0,1,2,0,1};
        #pragma unroll
        for (int tap = 0; tap < 5; ++tap)
            WPB[(((size_t)i * 25 + tap * 5 + (ic >> 5)) * 320 + oc) * 32 + (ic & 31)] =
                f2bf(t9[ky[tap] * 3 + kx[tap]]);
    } else if (bid < 2338) {               // ---- w_in transform
        int idx = (bid - 2278) * 256 + t;
        if (idx >= 3 * 160 * 32) return;
        int icl = idx & 31;
        int oc  = (idx >> 5) % 160;
        int kc  = idx / 5120;
        int k = kc * 32 + icl;
        short v = 0;
        if (k < 72) {
            int tap = k / 3, ic = k % 3;
            int ky = (tap < 21) ? tap / 7 : 3;
            int kx = (tap < 21) ? tap % 7 : tap - 21;
            v = f2bf(w_in[((oc * 3 + ic) * 7 + ky) * 7 + kx]);
        }
        WINP[idx] = v;
    } else if (bid < 2438) {               // ---- w_out1 transform
        int idx = (bid - 2338) * 256 + t;
        if (idx >= 5 * 160 * 32) return;
        int icl = idx & 31;
        int oc  = (idx >> 5) % 160;
        int kc  = idx / 5120;
        W1P[idx] = f2bf(w_out1[oc * 160 + kc * 32 + icl]);
    } else {                               // ---- w_out2 transform
        int idx = (bid - 2438) * 256 + t;
        if (idx >= 5 * 160 * 32) return;
        int icl = idx & 31;
        int oc  = (idx >> 5) % 160;
        int kc  = idx / 5120;
        W2P[idx] = (oc < 100) ? f2bf(w_out2[oc * 160 + kc * 32 + icl]) : (short)0;
    }
}

// masked 7x7 input conv, MFMA. grid (64,16) = (y,b), block 320 (5 waves).
// Writes h bf16 stream + bf16 relu mirror.
__global__ __launch_bounds__(320) void k_convin(const float* __restrict__ X,
                                                const short* __restrict__ WINP,
                                                short* __restrict__ hrout,
                                                short* __restrict__ Mout) {
    __shared__ float xls[3 * 4 * 72];   // [ic][r=ky][col], col = xg+3 (0..69)
    __shared__ short Bls[64 * 104];     // [px][k pad104]
    int y = blockIdx.x, b = blockIdx.y;
    int t = threadIdx.x;
    for (int i = t; i < 840; i += 320) {
        int col = i % 70; int r = (i / 70) % 4; int ic = i / 280;
        int xg = col - 3, yg = y + r - 3;
        float v = 0.f;
        if (xg >= 0 && xg < 64 && yg >= 0)
            v = X[((size_t)(b * 3 + ic) * 64 + yg) * 64 + xg];
        xls[(ic * 4 + r) * 72 + col] = v;
    }
    __syncthreads();
    for (int i = t; i < 6144; i += 320) {
        int k = i % 96; int px = i / 96;
        short v = 0;
        if (k < 72) {
            int tap = k / 3, ic = k % 3;
            int ky = (tap < 21) ? tap / 7 : 3;
            int kx = (tap < 21) ? tap % 7 : tap - 21;
            v = f2bf(xls[(ic * 4 + ky) * 72 + px + kx]);
        }
        Bls[px * 104 + k] = v;
    }
    __syncthreads();
    int lane = t & 63, wv = t >> 6;
    int lx = lane & 15, q = lane >> 4;
    f32x4 acc[2][4] = {};
    const short* wl = WINP + lx * 32 + q * 8;
    #pragma unroll
    for (int kc = 0; kc < 3; ++kc) {
        short8 aF[2], bF[4];
        aF[0] = *(const short8*)(wl + (kc * 160 + 32 * wv) * 32);
        aF[1] = *(const short8*)(wl + (kc * 160 + 32 * wv + 16) * 32);
        #pragma unroll
        for (int nt = 0; nt < 4; ++nt)
            bF[nt] = *(const short8*)&Bls[(nt * 16 + lx) * 104 + kc * 32 + q * 8];
        #pragma unroll
        for (int mt = 0; mt < 2; ++mt)
            #pragma unroll
            for (int nt = 0; nt < 4; ++nt)
                acc[mt][nt] = __builtin_amdgcn_mfma_f32_16x16x32_bf16(
                    aF[mt], bF[nt], acc[mt][nt], 0, 0, 0);
    }
    size_t rowbase = ((size_t)(b * 64 + y)) * 64 * 160;
    short* mrow = Mout + ((size_t)b * 65 + y + 1) * MROWP;
    #pragma unroll
    for (int mt = 0; mt < 2; ++mt) {
        int c0 = 32 * wv + mt * 16 + q * 4;
        #pragma unroll
        for (int nt = 0; nt < 4; ++nt) {
            int px = nt * 16 + lx;
            float4 o;
            o.x = acc[mt][nt][0]; o.y = acc[mt][nt][1];
            o.z = acc[mt][nt][2]; o.w = acc[mt][nt][3];
            union { short4v s; unsigned u[2]; } hv, mv;
            hv.u[0] = pk_bf16(o.x, o.y);
            hv.u[1] = pk_bf16(o.z, o.w);
            mv.u[0] = pk_bf16(fmaxf(o.x, 0.f), fmaxf(o.y, 0.f));
            mv.u[1] = pk_bf16(fmaxf(o.z, 0.f), fmaxf(o.w, 0.f));
            *(short4v*)&hrout[rowbase + (size_t)px * 160 + c0] = hv.s;
            *(short4v*)&mrow[(size_t)(px + 1) * 168 + c0] = mv.s;
        }
    }
}

// MFMA gated block conv. grid (32,16) = (y-pair,b), block 640 (10 waves).
// Wave w owns a-channels 16w..16w+15 and gate-channels 160+16w.. for ALL
// 128 px (rows y0,y0+1). Weights read once per block, 2-deep register
// pipeline. T14: residual hin prefetched before the staging barrier.
__global__ __launch_bounds__(640, 3) void k_blk(const short* __restrict__ hin,
                                                const short* __restrict__ Min,
                                                short* __restrict__ hout,
                                                short* __restrict__ Mout,
                                                const short* __restrict__ wP,
                                                int writeH) {
    __shared__ short in_s[3 * SLOT];   // 3 x 22528 B = 67584 B
    int b = blockIdx.y;
    int y0 = blockIdx.x * 2;
    int t = threadIdx.x;
    int w = t >> 6;               // 0..9 (oc-slice)
    int lane = t & 63;
    int lx = lane & 15, q = lane >> 4;
    int c0 = 16 * w + q * 4;

    // stage mirror rows y0..y0+2 into slots 0..2 (22 chunks x 1024 B per slot)
    #pragma unroll
    for (int m = 0; m < 3; ++m) {
        const short* src = Min + ((size_t)b * 65 + y0 + m) * MROWP;
        #pragma unroll
        for (int k = 0; k < 3; ++k) {
            int ch = k * 10 + w;
            if (ch < 22)
                gload_lds16(src + (size_t)(ch * 64 + lane) * 8, &in_s[m * SLOT + ch * 512]);
        }
    }

    // T14: residual prefetch (consumed in epilogue); drains at the barrier
    short4v hpre[2][4];
    #pragma unroll
    for (int r = 0; r < 2; ++r) {
        size_t rowbase = ((size_t)(b * 64 + y0 + r)) * 64 * 160;
        #pragma unroll
        for (int nt = 0; nt < 4; ++nt)
            hpre[r][nt] = *(const short4v*)
                &hin[rowbase + (size_t)(nt * 16 + lx) * 160 + c0];
    }

    f32x4 acc[2][8] = {};
    const short* wl = wP + lx * 32 + q * 8;
    const int dxs[5] = {-1, 0, 1, -1, 0};
    const int rws[5] = {0, 0, 0, 1, 1};

    short8 aF[2][2], bF[2][8];
    // 2-deep weight prologue: a-tile (oc 16w) + gate-tile (oc 160+16w)
    #pragma unroll
    for (int p = 0; p < 2; ++p) {
        const short* wk = wl + p * 10240;
        aF[p][0] = *(const short8*)(wk + (16 * w) * 32);
        aF[p][1] = *(const short8*)(wk + (160 + 16 * w) * 32);
    }
    __syncthreads();   // staging DMA complete (weights + hpre also drained)

    // B-fragments for step 0 (tap0: rws=0, dxs=-1): tiles 0-3 slot0, 4-7 slot1
    {
        int rb = lx * 168 + q * 8;
        #pragma unroll
        for (int nt = 0; nt < 4; ++nt) {
            bF[0][nt]     = *(const short8*)&in_s[rb + nt * 16 * 168];
            bF[0][nt + 4] = *(const short8*)&in_s[SLOT + rb + nt * 16 * 168];
        }
    }
    #pragma unroll
    for (int kk = 0; kk < 25; ++kk) {
        // 1-ahead B prefetch (LDS): 8 fragments (4 px-tiles x 2 rows)
        if (kk < 24) {
            int kn = kk + 1, tap = kn / 5, k5 = kn % 5;
            int base0 = rws[tap] ? SLOT : 0;
            int base1 = rws[tap] ? 2 * SLOT : SLOT;
            int rb = (1 + dxs[tap] + lx) * 168 + q * 8 + k5 * 32;
            #pragma unroll
            for (int nt = 0; nt < 4; ++nt) {
                bF[kn & 1][nt]     = *(const short8*)&in_s[base0 + rb + nt * 16 * 168];
                bF[kn & 1][nt + 4] = *(const short8*)&in_s[base1 + rb + nt * 16 * 168];
            }
        }
        __builtin_amdgcn_s_setprio(1);
        #pragma unroll
        for (int mt = 0; mt < 2; ++mt)
            #pragma unroll
            for (int nt = 0; nt < 8; ++nt)
                acc[mt][nt] = __builtin_amdgcn_mfma_f32_16x16x32_bf16(
                    aF[kk & 1][mt], bF[kk & 1][nt], acc[mt][nt], 0, 0, 0);
        __builtin_amdgcn_s_setprio(0);
        // 2-ahead weight refill into the buffer just consumed
        if (kk + 2 < 25) {
            const short* wk = wl + (kk + 2) * 10240;
            aF[kk & 1][0] = *(const short8*)(wk + (16 * w) * 32);
            aF[kk & 1][1] = *(const short8*)(wk + (160 + 16 * w) * 32);
        }
    }
    // epilogue: gating + residual rmw (bf16 stream) + bf16 relu-mirror write
    #pragma unroll
    for (int r = 0; r < 2; ++r) {
        int y = y0 + r;
        size_t rowbase = ((size_t)(b * 64 + y)) * 64 * 160;
        short* mrow = Mout + ((size_t)b * 65 + y + 1) * MROWP;
        #pragma unroll
        for (int nt = 0; nt < 4; ++nt) {
            int idx = r * 4 + nt;
            int px = nt * 16 + lx;
            size_t off = rowbase + (size_t)px * 160 + c0;
            short4v hp = hpre[r][nt];
            float4 o;
            o.x = bf2f(hp.x) + ftanh(acc[0][idx][0]) * fsigmoid(acc[1][idx][0]);
            o.y = bf2f(hp.y) + ftanh(acc[0][idx][1]) * fsigmoid(acc[1][idx][1]);
            o.z = bf2f(hp.z) + ftanh(acc[0][idx][2]) * fsigmoid(acc[1][idx][2]);
            o.w = bf2f(hp.w) + ftanh(acc[0][idx][3]) * fsigmoid(acc[1][idx][3]);
            union { short4v s; unsigned u[2]; } hv, mv;
            hv.u[0] = pk_bf16(o.x, o.y);
            hv.u[1] = pk_bf16(o.z, o.w);
            mv.u[0] = pk_bf16(fmaxf(o.x, 0.f), fmaxf(o.y, 0.f));
            mv.u[1] = pk_bf16(fmaxf(o.z, 0.f), fmaxf(o.w, 0.f));
            if (writeH) *(short4v*)&hout[off] = hv.s;
            *(short4v*)&mrow[(size_t)(px + 1) * 168 + c0] = mv.s;
        }
    }
}

// fused head: (mirror already holds relu(h) bf16) -> conv1x1(W1) -> relu ->
// conv1x1(W2) -> DMOL -> atomicAdd.  grid (64,16) = (y,b), block 320 (5 waves).
__global__ __launch_bounds__(320) void k_head(const short* __restrict__ Min,
                                              const short* __restrict__ W1P,
                                              const short* __restrict__ W2P,
                                              const float* __restrict__ X,
                                              float* __restrict__ out) {
    __shared__ __align__(16) char arenaA[29696]; // hls(21504) then Pls(26624)+lpls(3072)
    __shared__ short h2ls[64 * 168];             // 21504 B
    short* hls = (short*)arenaA;                 // [px][ic pad168] bf16 relu(h)
    float* Pls = (float*)arenaA;                 // [px][c pad104] fp32 params
    float* lpls = (float*)(arenaA + 26624);      // [px][m pad12]
    int y = blockIdx.x, b = blockIdx.y;
    int t = threadIdx.x;
    int wv = t >> 6;
    // stage relu(h) bf16 straight from mirror (x=1..64 of mirror row y+1)
    const short* src = Min + ((size_t)b * 65 + y + 1) * MROWP + 168;
    #pragma unroll
    for (int k = 0; k < 5; ++k)
        gload_lds16(src + ((size_t)k * 320 + t) * 8, &hls[(k * 320 + wv * 64) * 8]);
    __syncthreads();
    int lane = t & 63;
    int lx = lane & 15, q = lane >> 4;
    // GEMM1: h2 = relu(W1 * relu(h))
    {
        f32x4 acc[2][4] = {};
        const short* wl = W1P + lx * 32 + q * 8;
        #pragma unroll
        for (int kc = 0; kc < 5; ++kc) {
            short8 aF[2], bF[4];
            aF[0] = *(const short8*)(wl + (kc * 160 + 32 * wv) * 32);
            aF[1] = *(const short8*)(wl + (kc * 160 + 32 * wv + 16) * 32);
            #pragma unroll
            for (int nt = 0; nt < 4; ++nt)
                bF[nt] = *(const short8*)&hls[(nt * 16 + lx) * 168 + kc * 32 + q * 8];
            #pragma unroll
            for (int mt = 0; mt < 2; ++mt)
                #pragma unroll
                for (int nt = 0; nt < 4; ++nt)
                    acc[mt][nt] = __builtin_amdgcn_mfma_f32_16x16x32_bf16(
                        aF[mt], bF[nt], acc[mt][nt], 0, 0, 0);
        }
        #pragma unroll
        for (int mt = 0; mt < 2; ++mt) {
            int c0 = 32 * wv + mt * 16 + q * 4;
            #pragma unroll
            for (int nt = 0; nt < 4; ++nt) {
                int px = nt * 16 + lx;
                union { short4v s; unsigned u[2]; } sv;
                sv.u[0] = pk_bf16(fmaxf(acc[mt][nt][0], 0.f), fmaxf(acc[mt][nt][1], 0.f));
                sv.u[1] = pk_bf16(fmaxf(acc[mt][nt][2], 0.f), fmaxf(acc[mt][nt][3], 0.f));
                *(short4v*)&h2ls[px * 168 + c0] = sv.s;
            }
        }
    }
    __syncthreads();
    // GEMM2: params = W2 * h2   (oc padded to 160; only c<100 stored)
    {
        f32x4 acc[2][4] = {};
        const short* wl = W2P + lx * 32 + q * 8;
        #pragma unroll
        for (int kc = 0; kc < 5; ++kc) {
            short8 aF[2], bF[4];
            aF[0] = *(const short8*)(wl + (kc * 160 + 32 * wv) * 32);
            aF[1] = *(const short8*)(wl + (kc * 160 + 32 * wv + 16) * 32);
            #pragma unroll
            for (int nt = 0; nt < 4; ++nt)
                bF[nt] = *(const short8*)&h2ls[(nt * 16 + lx) * 168 + kc * 32 + q * 8];
            #pragma unroll
            for (int mt = 0; mt < 2; ++mt)
                #pragma unroll
                for (int nt = 0; nt < 4; ++nt)
                    acc[mt][nt] = __builtin_amdgcn_mfma_f32_16x16x32_bf16(
                        aF[mt], bF[nt], acc[mt][nt], 0, 0, 0);
        }
        #pragma unroll
        for (int mt = 0; mt < 2; ++mt) {
            int c0 = 32 * wv + mt * 16 + q * 4;
            if (c0 < 100) {
                #pragma unroll
                for (int nt = 0; nt < 4; ++nt) {
                    int px = nt * 16 + lx;
                    float4 o;
                    o.x = acc[mt][nt][0]; o.y = acc[mt][nt][1];
                    o.z = acc[mt][nt][2]; o.w = acc[mt][nt][3];
                    *(float4*)&Pls[px * 104 + c0] = o;
                }
            }
        }
    }
    __syncthreads();
    // DMOL: 640 (px, mixture) tasks over 320 threads
    const float LOG127P5 = 4.8481163504f;   // ln(127.5)
    #pragma unroll
    for (int it = 0; it < 2; ++it) {
        int tk = t + it * 320;
        int px = tk & 63, m = tk >> 6;
        const float* pp = &Pls[px * 104];
        float xs[3];
        #pragma unroll
        for (int c = 0; c < 3; ++c)
            xs[c] = X[((size_t)(b * 3 + c)) * 4096 + (size_t)y * 64 + px];
        float mx = pp[0];
        #pragma unroll
        for (int j = 1; j < 10; ++j) mx = fmaxf(mx, pp[j]);
        float se = 0.f;
        #pragma unroll
        for (int j = 0; j < 10; ++j) se += fexp(pp[j] - mx);
        float lse = mx + flog(se);
        float sum = pp[m] - lse;
        float mean0 = pp[10 + m];
        float mean1 = pp[40 + m];
        float mean2 = pp[70 + m];
        float ls0 = fmaxf(pp[20 + m], -7.f);
        float ls1 = fmaxf(pp[50 + m], -7.f);
        float ls2 = fmaxf(pp[80 + m], -7.f);
        float c0 = ftanh(pp[30 + m]);
        float c1 = ftanh(pp[60 + m]);
        float c2 = ftanh(pp[90 + m]);
        float mu[3], lsv[3];
        mu[0] = mean0;
        mu[1] = mean1 + c0 * xs[0];
        mu[2] = mean2 + c1 * xs[0] + c2 * xs[1];
        lsv[0] = ls0; lsv[1] = ls1; lsv[2] = ls2;
        #pragma unroll
        for (int ci = 0; ci < 3; ++ci) {
            float cent = xs[ci] - mu[ci];
            float inv = fexp(-lsv[ci]);
            float plus_in = inv * (cent + 1.f / 255.f);
            float min_in = inv * (cent - 1.f / 255.f);
            float cdf_delta = fsigmoid(plus_in) - fsigmoid(min_in);
            float log_cdf_plus = plus_in - fsoftplus(plus_in);
            float log_om_cdf = -fsoftplus(min_in);
            float mid = inv * cent;
            float log_pdf_mid = mid - lsv[ci] - 2.f * fsoftplus(mid);
            float lpi = (cdf_delta > 1e-5f) ? flog(fmaxf(cdf_delta, 1e-12f))
                                            : (log_pdf_mid - LOG127P5);
            float lpc = (xs[ci] < -0.999f) ? log_cdf_plus
                       : ((xs[ci] > 0.999f) ? log_om_cdf : lpi);
            sum += lpc;
        }
        lpls[px * 12 + m] = sum;
    }
    __syncthreads();
    if (t < 64) {
        int px = t;
        float mx2 = lpls[px * 12];
        #pragma unroll
        for (int m = 1; m < 10; ++m) mx2 = fmaxf(mx2, lpls[px * 12 + m]);
        float se2 = 0.f;
        #pragma unroll
        for (int m = 0; m < 10; ++m) se2 += fexp(lpls[px * 12 + m] - mx2);
        float lp = mx2 + flog(se2);
        #pragma unroll
        for (int off = 32; off > 0; off >>= 1) lp += __shfl_down(lp, off, 64);
        if (t == 0) atomicAdd(&out[b], lp);
    }
}

extern "C" void kernel_launch(void* const* d_in, const int* in_sizes, int n_in,
                              void* d_out, int out_size, void* d_ws, size_t ws_size,
                              hipStream_t stream) {
    const float* samples = (const float*)d_in[0];
    const float* w_in    = (const float*)d_in[1];
    const float* w_blk   = (const float*)d_in[2];
    const float* w_out1  = (const float*)d_in[3];
    const float* w_out2  = (const float*)d_in[4];
    char* ws = (char*)d_ws;
    float* X    = (float*)(ws + X_OFF);
    short* WINP = (short*)(ws + WINP_OFF);
    short* W1P  = (short*)(ws + W1P_OFF);
    short* W2P  = (short*)(ws + W2P_OFF);
    short* WPB  = (short*)(ws + WPB_OFF);
    short* HRA  = (short*)(ws + HRA_OFF);
    short* HRB  = (short*)(ws + HRB_OFF);
    short* MA   = (short*)(ws + MA_OFF);
    short* MB   = (short*)(ws + MB_OFF);
    float* fout = (float*)d_out;

    k_setup<<<2538, 256, 0, stream>>>(samples, w_in, w_blk, w_out1, w_out2,
                                      X, WINP, WPB, W1P, W2P, MA, MB,
                                      fout, out_size);

    k_convin<<<dim3(64, 16), 320, 0, stream>>>(X, WINP, HRA, MA);

    short* a = HRA; short* bq = HRB;
    short* ma = MA; short* mb = MB;
    for (int i = 0; i < 5; i++) {
        k_blk<<<dim3(32, 16), 640, 0, stream>>>(a, ma, bq, mb,
                                                WPB + (size_t)i * 25 * 320 * 32,
                                                (i < 4) ? 1 : 0);
        short* tf = a; a = bq; bq = tf;
        short* tm = ma; ma = mb; mb = tm;
    }
    // final h mirror is in ma (= MB after 5 swaps)
    k_head<<<dim3(64, 16), 320, 0, stream>>>(ma, W1P, W2P, X, fout);
}

// Round 13
// 306.331 us; speedup vs baseline: 1.1797x; 1.0789x over previous
//
#include <hip/hip_runtime.h>
#include <math.h>

// ---------------------------------------------------------------------------
// PixelCNN (5 gated residual blocks) + DMOL logprob.  Round 17:
//   - k_blk (layers 0-3) = exact round-11 structure (measured best 43.7 us:
//     10 waves, wave w = 16 a-oc + 16 gate-oc x 128 px, 16x16x32, 2-deep aF,
//     1-ahead bF, inline epilogue hin loads — hpre retired after 2 failures).
//   - NEW: final layer fused with the head (k_blk_head): epilogue writes
//     relu(h5) bf16 into LDS (aliasing the dead conv arena), then GEMM1 ->
//     GEMM2 -> DMOL -> atomicAdd in-block (2 rows x 5-wave head structure).
//     Kills k_head launch + final mirror write + re-read (~42 MB round trip).
//   - kept: k_setup merge (+d_out zero), bf16 residual stream + relu-mirror,
//     global_load_lds staging.
// ---------------------------------------------------------------------------

using short8  = __attribute__((ext_vector_type(8))) short;
using short4v = __attribute__((ext_vector_type(4))) short;
using f32x4   = __attribute__((ext_vector_type(4))) float;

static constexpr float L2E = 1.44269504088896f;   // log2(e)
static constexpr float LN2 = 0.69314718055995f;   // ln(2)

__device__ __forceinline__ float fexp2(float x) { return __builtin_amdgcn_exp2f(x); }
__device__ __forceinline__ float flog2(float x) { return __builtin_amdgcn_logf(x); }
__device__ __forceinline__ float frcp(float x)  { return __builtin_amdgcn_rcpf(x); }
__device__ __forceinline__ float fexp(float x)  { return fexp2(x * L2E); }
__device__ __forceinline__ float flog(float x)  { return flog2(x) * LN2; }
__device__ __forceinline__ float fsigmoid(float x) { return frcp(1.f + fexp2(-x * L2E)); }
__device__ __forceinline__ float ftanh(float x)    { return 1.f - 2.f * frcp(1.f + fexp2(x * (2.f * L2E))); }
__device__ __forceinline__ float fsoftplus(float z) {
    float e = fexp2(-fabsf(z) * L2E);
    return fmaxf(z, 0.f) + flog2(1.f + e) * LN2;
}

// pack two fp32 -> packed bf16 pair (a in low, b in high)
__device__ __forceinline__ unsigned pk_bf16(float a, float b) {
    union { float f; unsigned u; } ua, ub; ua.f = a; ub.f = b;
    return __builtin_amdgcn_perm(ub.u + 0x7fffu, ua.u + 0x7fffu, 0x07060302u);
}

__device__ __forceinline__ short f2bf(float f) {
    union { float f; unsigned u; } v; v.f = f;
    unsigned r = (v.u + 0x7fffu + ((v.u >> 16) & 1u)) >> 16;
    return (short)r;
}

__device__ __forceinline__ float bf2f(short s) {
    union { float f; unsigned u; } v;
    v.u = ((unsigned)(unsigned short)s) << 16;
    return v.f;
}

// async global->LDS DMA, 16B per lane; lds ptr must be wave-uniform
__device__ __forceinline__ void gload_lds16(const void* g, void* l) {
    __builtin_amdgcn_global_load_lds(
        (const __attribute__((address_space(1))) unsigned int*)g,
        (__attribute__((address_space(3))) unsigned int*)l, 16, 0, 0);
}

// workspace layout (bytes), 16B-aligned
static constexpr size_t X_OFF    = 0;             // 16*3*4096*4    = 786432
static constexpr size_t WINP_OFF = 786432;        // 3*160*32*2     = 30720
static constexpr size_t W1P_OFF  = 817152;        // 5*160*32*2     = 51200
static constexpr size_t W2P_OFF  = 868352;        // 5*160*32*2     = 51200
static constexpr size_t WPB_OFF  = 919552;        // 5*25*320*32*2  = 2560000
// bf16 residual stream h: [b][y][x][160], 16*4096*160*2 = 20971520 each
static constexpr size_t HRA_OFF  = 3479552;
static constexpr size_t HRB_OFF  = 24451072;
// bf16 relu-mirror: [b][row 0..64][x 0..65][168], row0 & x in {0,65} are zeros
// 16*65*66*168*2 = 23063040 B (+8192 slack for unconditional DMA over-read)
static constexpr size_t MA_OFF   = 45422592;
static constexpr size_t MB_OFF   = 68493824;      // end ~91.6 MB

static constexpr int MROWP = 66 * 168;            // mirror row pitch (shorts) = 11088
static constexpr int SLOT  = 11264;               // staging slot pitch (shorts) = 22528 B

// ---------------------------------------------------------------------------
// k_setup: all preprocessing in ONE launch (+ d_out zeroing).
// ---------------------------------------------------------------------------
__global__ void k_setup(const float* __restrict__ s,
                        const float* __restrict__ w_in,
                        const float* __restrict__ w_blk,
                        const float* __restrict__ w_out1,
                        const float* __restrict__ w_out2,
                        float* __restrict__ X,
                        short* __restrict__ WINP,
                        short* __restrict__ WPB,
                        short* __restrict__ W1P,
                        short* __restrict__ W2P,
                        short* __restrict__ MA,
                        short* __restrict__ MB,
                        float* __restrict__ out, int outn) {
    int bid = blockIdx.x;
    int t = threadIdx.x;
    if (bid < 768) {                       // ---- prep X (+ out zero)
        if (bid == 0 && t < outn) out[t] = 0.f;
        int i = bid * 256 + t;
        if (i < 16 * 3 * 4096) X[i] = 2.f * s[i] - 1.f;
    } else if (bid < 1278) {               // ---- mirror border zero
        int idx = (bid - 768) * 256 + t;
        if (idx >= 2 * 16 * 194 * 21) return;
        int ch   = idx % 21;
        int cell = (idx / 21) % 194;
        int b    = (idx / (21 * 194)) % 16;
        short* M = (idx >= 16 * 194 * 21) ? MB : MA;
        int row, x;
        if (cell < 66) { row = 0; x = cell; }
        else { row = 1 + (cell - 66) / 2; x = ((cell - 66) & 1) ? 65 : 0; }
        short8 z = {};
        *(short8*)&M[((size_t)b * 65 + row) * MROWP + (size_t)x * 168 + ch * 8] = z;
    } else if (bid < 2278) {               // ---- w_blk transform
        int idx = (bid - 1278) * 256 + t;
        if (idx >= 5 * 320 * 160) return;
        int ic = idx % 160;
        int oc = (idx / 160) % 320;
        int i  = idx / (160 * 320);
        const float* p = w_blk + (size_t)idx * 9;
        float t9[9];
        #pragma unroll
        for (int j = 0; j < 9; ++j) t9[j] = p[j];
        const int ky[5] = {0,0,0,1,1}, kx[5] = {0,1,2,0,1};
        #pragma unroll
        for (int tap = 0; tap < 5; ++tap)
            WPB[(((size_t)i * 25 + tap * 5 + (ic >> 5)) * 320 + oc) * 32 + (ic & 31)] =
                f2bf(t9[ky[tap] * 3 + kx[tap]]);
    } else if (bid < 2338) {               // ---- w_in transform
        int idx = (bid - 2278) * 256 + t;
        if (idx >= 3 * 160 * 32) return;
        int icl = idx & 31;
        int oc  = (idx >> 5) % 160;
        int kc  = idx / 5120;
        int k = kc * 32 + icl;
        short v = 0;
        if (k < 72) {
            int tap = k / 3, ic = k % 3;
            int ky = (tap < 21) ? tap / 7 : 3;
            int kx = (tap < 21) ? tap % 7 : tap - 21;
            v = f2bf(w_in[((oc * 3 + ic) * 7 + ky) * 7 + kx]);
        }
        WINP[idx] = v;
    } else if (bid < 2438) {               // ---- w_out1 transform
        int idx = (bid - 2338) * 256 + t;
        if (idx >= 5 * 160 * 32) return;
        int icl = idx & 31;
        int oc  = (idx >> 5) % 160;
        int kc  = idx / 5120;
        W1P[idx] = f2bf(w_out1[oc * 160 + kc * 32 + icl]);
    } else {                               // ---- w_out2 transform
        int idx = (bid - 2438) * 256 + t;
        if (idx >= 5 * 160 * 32) return;
        int icl = idx & 31;
        int oc  = (idx >> 5) % 160;
        int kc  = idx / 5120;
        W2P[idx] = (oc < 100) ? f2bf(w_out2[oc * 160 + kc * 32 + icl]) : (short)0;
    }
}

// masked 7x7 input conv, MFMA. grid (64,16) = (y,b), block 320 (5 waves).
// Writes h bf16 stream + bf16 relu mirror.
__global__ __launch_bounds__(320) void k_convin(const float* __restrict__ X,
                                                const short* __restrict__ WINP,
                                                short* __restrict__ hrout,
                                                short* __restrict__ Mout) {
    __shared__ float xls[3 * 4 * 72];   // [ic][r=ky][col], col = xg+3 (0..69)
    __shared__ short Bls[64 * 104];     // [px][k pad104]
    int y = blockIdx.x, b = blockIdx.y;
    int t = threadIdx.x;
    for (int i = t; i < 840; i += 320) {
        int col = i % 70; int r = (i / 70) % 4; int ic = i / 280;
        int xg = col - 3, yg = y + r - 3;
        float v = 0.f;
        if (xg >= 0 && xg < 64 && yg >= 0)
            v = X[((size_t)(b * 3 + ic) * 64 + yg) * 64 + xg];
        xls[(ic * 4 + r) * 72 + col] = v;
    }
    __syncthreads();
    for (int i = t; i < 6144; i += 320) {
        int k = i % 96; int px = i / 96;
        short v = 0;
        if (k < 72) {
            int tap = k / 3, ic = k % 3;
            int ky = (tap < 21) ? tap / 7 : 3;
            int kx = (tap < 21) ? tap % 7 : tap - 21;
            v = f2bf(xls[(ic * 4 + ky) * 72 + px + kx]);
        }
        Bls[px * 104 + k] = v;
    }
    __syncthreads();
    int lane = t & 63, wv = t >> 6;
    int lx = lane & 15, q = lane >> 4;
    f32x4 acc[2][4] = {};
    const short* wl = WINP + lx * 32 + q * 8;
    #pragma unroll
    for (int kc = 0; kc < 3; ++kc) {
        short8 aF[2], bF[4];
        aF[0] = *(const short8*)(wl + (kc * 160 + 32 * wv) * 32);
        aF[1] = *(const short8*)(wl + (kc * 160 + 32 * wv + 16) * 32);
        #pragma unroll
        for (int nt = 0; nt < 4; ++nt)
            bF[nt] = *(const short8*)&Bls[(nt * 16 + lx) * 104 + kc * 32 + q * 8];
        #pragma unroll
        for (int mt = 0; mt < 2; ++mt)
            #pragma unroll
            for (int nt = 0; nt < 4; ++nt)
                acc[mt][nt] = __builtin_amdgcn_mfma_f32_16x16x32_bf16(
                    aF[mt], bF[nt], acc[mt][nt], 0, 0, 0);
    }
    size_t rowbase = ((size_t)(b * 64 + y)) * 64 * 160;
    short* mrow = Mout + ((size_t)b * 65 + y + 1) * MROWP;
    #pragma unroll
    for (int mt = 0; mt < 2; ++mt) {
        int c0 = 32 * wv + mt * 16 + q * 4;
        #pragma unroll
        for (int nt = 0; nt < 4; ++nt) {
            int px = nt * 16 + lx;
            float4 o;
            o.x = acc[mt][nt][0]; o.y = acc[mt][nt][1];
            o.z = acc[mt][nt][2]; o.w = acc[mt][nt][3];
            union { short4v s; unsigned u[2]; } hv, mv;
            hv.u[0] = pk_bf16(o.x, o.y);
            hv.u[1] = pk_bf16(o.z, o.w);
            mv.u[0] = pk_bf16(fmaxf(o.x, 0.f), fmaxf(o.y, 0.f));
            mv.u[1] = pk_bf16(fmaxf(o.z, 0.f), fmaxf(o.w, 0.f));
            *(short4v*)&hrout[rowbase + (size_t)px * 160 + c0] = hv.s;
            *(short4v*)&mrow[(size_t)(px + 1) * 168 + c0] = mv.s;
        }
    }
}

// MFMA gated block conv (layers 0-3). grid (32,16), block 640 (10 waves).
// Wave w owns a-channels 16w..16w+15 and gate-channels 160+16w.. for ALL
// 128 px (rows y0,y0+1). Weights read once per block, 2-deep pipeline.
// Exact round-11 structure (inline epilogue hin loads).
__global__ __launch_bounds__(640, 3) void k_blk(const short* __restrict__ hin,
                                                const short* __restrict__ Min,
                                                short* __restrict__ hout,
                                                short* __restrict__ Mout,
                                                const short* __restrict__ wP) {
    __shared__ short in_s[3 * SLOT];   // 3 x 22528 B = 67584 B
    int b = blockIdx.y;
    int y0 = blockIdx.x * 2;
    int t = threadIdx.x;
    int w = t >> 6;               // 0..9 (oc-slice)
    int lane = t & 63;
    int lx = lane & 15, q = lane >> 4;

    // stage mirror rows y0..y0+2 into slots 0..2 (22 chunks x 1024 B per slot)
    #pragma unroll
    for (int m = 0; m < 3; ++m) {
        const short* src = Min + ((size_t)b * 65 + y0 + m) * MROWP;
        #pragma unroll
        for (int k = 0; k < 3; ++k) {
            int ch = k * 10 + w;
            if (ch < 22)
                gload_lds16(src + (size_t)(ch * 64 + lane) * 8, &in_s[m * SLOT + ch * 512]);
        }
    }

    f32x4 acc[2][8] = {};
    const short* wl = wP + lx * 32 + q * 8;
    const int dxs[5] = {-1, 0, 1, -1, 0};
    const int rws[5] = {0, 0, 0, 1, 1};

    short8 aF[2][2], bF[2][8];
    // 2-deep weight prologue: a-tile (oc 16w) + gate-tile (oc 160+16w)
    #pragma unroll
    for (int p = 0; p < 2; ++p) {
        const short* wk = wl + p * 10240;
        aF[p][0] = *(const short8*)(wk + (16 * w) * 32);
        aF[p][1] = *(const short8*)(wk + (160 + 16 * w) * 32);
    }
    __syncthreads();   // staging DMA complete (weights also drained here)

    // B-fragments for step 0 (tap0: rws=0, dxs=-1): tiles 0-3 slot0, 4-7 slot1
    {
        int rb = lx * 168 + q * 8;
        #pragma unroll
        for (int nt = 0; nt < 4; ++nt) {
            bF[0][nt]     = *(const short8*)&in_s[rb + nt * 16 * 168];
            bF[0][nt + 4] = *(const short8*)&in_s[SLOT + rb + nt * 16 * 168];
        }
    }
    #pragma unroll
    for (int kk = 0; kk < 25; ++kk) {
        // 1-ahead B prefetch (LDS): 8 fragments (4 px-tiles x 2 rows)
        if (kk < 24) {
            int kn = kk + 1, tap = kn / 5, k5 = kn % 5;
            int base0 = rws[tap] ? SLOT : 0;
            int base1 = rws[tap] ? 2 * SLOT : SLOT;
            int rb = (1 + dxs[tap] + lx) * 168 + q * 8 + k5 * 32;
            #pragma unroll
            for (int nt = 0; nt < 4; ++nt) {
                bF[kn & 1][nt]     = *(const short8*)&in_s[base0 + rb + nt * 16 * 168];
                bF[kn & 1][nt + 4] = *(const short8*)&in_s[base1 + rb + nt * 16 * 168];
            }
        }
        __builtin_amdgcn_s_setprio(1);
        #pragma unroll
        for (int mt = 0; mt < 2; ++mt)
            #pragma unroll
            for (int nt = 0; nt < 8; ++nt)
                acc[mt][nt] = __builtin_amdgcn_mfma_f32_16x16x32_bf16(
                    aF[kk & 1][mt], bF[kk & 1][nt], acc[mt][nt], 0, 0, 0);
        __builtin_amdgcn_s_setprio(0);
        // 2-ahead weight refill into the buffer just consumed
        if (kk + 2 < 25) {
            const short* wk = wl + (kk + 2) * 10240;
            aF[kk & 1][0] = *(const short8*)(wk + (16 * w) * 32);
            aF[kk & 1][1] = *(const short8*)(wk + (160 + 16 * w) * 32);
        }
    }
    // epilogue: gating + residual rmw (bf16 stream) + bf16 relu-mirror write
    int c0 = 16 * w + q * 4;
    #pragma unroll
    for (int r = 0; r < 2; ++r) {
        int y = y0 + r;
        size_t rowbase = ((size_t)(b * 64 + y)) * 64 * 160;
        short* mrow = Mout + ((size_t)b * 65 + y + 1) * MROWP;
        #pragma unroll
        for (int nt = 0; nt < 4; ++nt) {
            int idx = r * 4 + nt;
            int px = nt * 16 + lx;
            size_t off = rowbase + (size_t)px * 160 + c0;
            short4v hp = *(const short4v*)&hin[off];
            float4 o;
            o.x = bf2f(hp.x) + ftanh(acc[0][idx][0]) * fsigmoid(acc[1][idx][0]);
            o.y = bf2f(hp.y) + ftanh(acc[0][idx][1]) * fsigmoid(acc[1][idx][1]);
            o.z = bf2f(hp.z) + ftanh(acc[0][idx][2]) * fsigmoid(acc[1][idx][2]);
            o.w = bf2f(hp.w) + ftanh(acc[0][idx][3]) * fsigmoid(acc[1][idx][3]);
            union { short4v s; unsigned u[2]; } hv, mv;
            hv.u[0] = pk_bf16(o.x, o.y);
            hv.u[1] = pk_bf16(o.z, o.w);
            mv.u[0] = pk_bf16(fmaxf(o.x, 0.f), fmaxf(o.y, 0.f));
            mv.u[1] = pk_bf16(fmaxf(o.z, 0.f), fmaxf(o.w, 0.f));
            *(short4v*)&hout[off] = hv.s;
            *(short4v*)&mrow[(size_t)(px + 1) * 168 + c0] = mv.s;
        }
    }
}

// Final layer FUSED with the head. Same k-loop as k_blk; epilogue keeps
// relu(h5) in LDS; then GEMM1(W1)+relu -> GEMM2(W2) -> DMOL -> atomicAdd.
// LDS arena phases: conv in_s [0,67584) -> hls [0,43008) -> h2ls
// [43008,86016) -> Pls [0,53248) -> lpls [86016,92160).
__global__ __launch_bounds__(640, 3) void k_blk_head(const short* __restrict__ hin,
                                                     const short* __restrict__ Min,
                                                     const short* __restrict__ wP,
                                                     const short* __restrict__ W1P,
                                                     const short* __restrict__ W2P,
                                                     const float* __restrict__ X,
                                                     float* __restrict__ out) {
    __shared__ __align__(16) char arena[92160];
    short* in_s = (short*)arena;
    int b = blockIdx.y;
    int y0 = blockIdx.x * 2;
    int t = threadIdx.x;
    int w = t >> 6;               // 0..9
    int lane = t & 63;
    int lx = lane & 15, q = lane >> 4;

    // stage mirror rows y0..y0+2
    #pragma unroll
    for (int m = 0; m < 3; ++m) {
        const short* src = Min + ((size_t)b * 65 + y0 + m) * MROWP;
        #pragma unroll
        for (int k = 0; k < 3; ++k) {
            int ch = k * 10 + w;
            if (ch < 22)
                gload_lds16(src + (size_t)(ch * 64 + lane) * 8, &in_s[m * SLOT + ch * 512]);
        }
    }

    f32x4 acc[2][8] = {};
    const short* wl = wP + lx * 32 + q * 8;
    const int dxs[5] = {-1, 0, 1, -1, 0};
    const int rws[5] = {0, 0, 0, 1, 1};

    short8 aF[2][2], bF[2][8];
    #pragma unroll
    for (int p = 0; p < 2; ++p) {
        const short* wk = wl + p * 10240;
        aF[p][0] = *(const short8*)(wk + (16 * w) * 32);
        aF[p][1] = *(const short8*)(wk + (160 + 16 * w) * 32);
    }
    __syncthreads();

    {
        int rb = lx * 168 + q * 8;
        #pragma unroll
        for (int nt = 0; nt < 4; ++nt) {
            bF[0][nt]     = *(const short8*)&in_s[rb + nt * 16 * 168];
            bF[0][nt + 4] = *(const short8*)&in_s[SLOT + rb + nt * 16 * 168];
        }
    }
    #pragma unroll
    for (int kk = 0; kk < 25; ++kk) {
        if (kk < 24) {
            int kn = kk + 1, tap = kn / 5, k5 = kn % 5;
            int base0 = rws[tap] ? SLOT : 0;
            int base1 = rws[tap] ? 2 * SLOT : SLOT;
            int rb = (1 + dxs[tap] + lx) * 168 + q * 8 + k5 * 32;
            #pragma unroll
            for (int nt = 0; nt < 4; ++nt) {
                bF[kn & 1][nt]     = *(const short8*)&in_s[base0 + rb + nt * 16 * 168];
                bF[kn & 1][nt + 4] = *(const short8*)&in_s[base1 + rb + nt * 16 * 168];
            }
        }
        __builtin_amdgcn_s_setprio(1);
        #pragma unroll
        for (int mt = 0; mt < 2; ++mt)
            #pragma unroll
            for (int nt = 0; nt < 8; ++nt)
                acc[mt][nt] = __builtin_amdgcn_mfma_f32_16x16x32_bf16(
                    aF[kk & 1][mt], bF[kk & 1][nt], acc[mt][nt], 0, 0, 0);
        __builtin_amdgcn_s_setprio(0);
        if (kk + 2 < 25) {
            const short* wk = wl + (kk + 2) * 10240;
            aF[kk & 1][0] = *(const short8*)(wk + (16 * w) * 32);
            aF[kk & 1][1] = *(const short8*)(wk + (160 + 16 * w) * 32);
        }
    }
    __syncthreads();   // all in_s reads done before hls overwrites the arena

    // epilogue: h5 = hin + gate; relu(h5) bf16 -> hls [r*64+px][168]
    short* hls = (short*)arena;
    int c0 = 16 * w + q * 4;
    #pragma unroll
    for (int r = 0; r < 2; ++r) {
        size_t rowbase = ((size_t)(b * 64 + y0 + r)) * 64 * 160;
        #pragma unroll
        for (int nt = 0; nt < 4; ++nt) {
            int idx = r * 4 + nt;
            int px = nt * 16 + lx;
            short4v hp = *(const short4v*)&hin[rowbase + (size_t)px * 160 + c0];
            float4 o;
            o.x = bf2f(hp.x) + ftanh(acc[0][idx][0]) * fsigmoid(acc[1][idx][0]);
            o.y = bf2f(hp.y) + ftanh(acc[0][idx][1]) * fsigmoid(acc[1][idx][1]);
            o.z = bf2f(hp.z) + ftanh(acc[0][idx][2]) * fsigmoid(acc[1][idx][2]);
            o.w = bf2f(hp.w) + ftanh(acc[0][idx][3]) * fsigmoid(acc[1][idx][3]);
            union { short4v s; unsigned u[2]; } mv;
            mv.u[0] = pk_bf16(fmaxf(o.x, 0.f), fmaxf(o.y, 0.f));
            mv.u[1] = pk_bf16(fmaxf(o.z, 0.f), fmaxf(o.w, 0.f));
            *(short4v*)&hls[(size_t)(r * 64 + px) * 168 + c0] = mv.s;
        }
    }
    __syncthreads();

    // head: 2 rows x 5-wave k_head structure. g = row, w5 = oc-slice wave.
    int g  = (w >= 5) ? 1 : 0;
    int w5 = w - 5 * g;
    short* h2ls = (short*)(arena + 43008);
    // GEMM1: h2 = relu(W1 * relu(h5))
    {
        f32x4 hacc[2][4] = {};
        const short* wl1 = W1P + lx * 32 + q * 8;
        #pragma unroll
        for (int kc = 0; kc < 5; ++kc) {
            short8 a1[2], b1[4];
            a1[0] = *(const short8*)(wl1 + (kc * 160 + 32 * w5) * 32);
            a1[1] = *(const short8*)(wl1 + (kc * 160 + 32 * w5 + 16) * 32);
            #pragma unroll
            for (int nt = 0; nt < 4; ++nt)
                b1[nt] = *(const short8*)&hls[(size_t)(g * 64 + nt * 16 + lx) * 168 + kc * 32 + q * 8];
            #pragma unroll
            for (int mt = 0; mt < 2; ++mt)
                #pragma unroll
                for (int nt = 0; nt < 4; ++nt)
                    hacc[mt][nt] = __builtin_amdgcn_mfma_f32_16x16x32_bf16(
                        a1[mt], b1[nt], hacc[mt][nt], 0, 0, 0);
        }
        #pragma unroll
        for (int mt = 0; mt < 2; ++mt) {
            int cc = 32 * w5 + mt * 16 + q * 4;
            #pragma unroll
            for (int nt = 0; nt < 4; ++nt) {
                int px = nt * 16 + lx;
                union { short4v s; unsigned u[2]; } sv;
                sv.u[0] = pk_bf16(fmaxf(hacc[mt][nt][0], 0.f), fmaxf(hacc[mt][nt][1], 0.f));
                sv.u[1] = pk_bf16(fmaxf(hacc[mt][nt][2], 0.f), fmaxf(hacc[mt][nt][3], 0.f));
                *(short4v*)&h2ls[(size_t)(g * 64 + px) * 168 + cc] = sv.s;
            }
        }
    }
    __syncthreads();
    // GEMM2: params = W2 * h2 (Pls aliases hls region — hls dead now)
    float* Pls = (float*)arena;
    {
        f32x4 hacc[2][4] = {};
        const short* wl2 = W2P + lx * 32 + q * 8;
        #pragma unroll
        for (int kc = 0; kc < 5; ++kc) {
            short8 a2[2], b2[4];
            a2[0] = *(const short8*)(wl2 + (kc * 160 + 32 * w5) * 32);
            a2[1] = *(const short8*)(wl2 + (kc * 160 + 32 * w5 + 16) * 32);
            #pragma unroll
            for (int nt = 0; nt < 4; ++nt)
                b2[nt] = *(const short8*)&h2ls[(size_t)(g * 64 + nt * 16 + lx) * 168 + kc * 32 + q * 8];
            #pragma unroll
            for (int mt = 0; mt < 2; ++mt)
                #pragma unroll
                for (int nt = 0; nt < 4; ++nt)
                    hacc[mt][nt] = __builtin_amdgcn_mfma_f32_16x16x32_bf16(
                        a2[mt], b2[nt], hacc[mt][nt], 0, 0, 0);
        }
        #pragma unroll
        for (int mt = 0; mt < 2; ++mt) {
            int cc = 32 * w5 + mt * 16 + q * 4;
            if (cc < 100) {
                #pragma unroll
                for (int nt = 0; nt < 4; ++nt) {
                    int px = nt * 16 + lx;
                    float4 o;
                    o.x = hacc[mt][nt][0]; o.y = hacc[mt][nt][1];
                    o.z = hacc[mt][nt][2]; o.w = hacc[mt][nt][3];
                    *(float4*)&Pls[(size_t)(g * 64 + px) * 104 + cc] = o;
                }
            }
        }
    }
    __syncthreads();
    // DMOL: 1280 (r, px, mixture) tasks over 640 threads
    float* lpls = (float*)(arena + 86016);
    const float LOG127P5 = 4.8481163504f;   // ln(127.5)
    #pragma unroll
    for (int it = 0; it < 2; ++it) {
        int tk = t + it * 640;
        int px = tk & 63;
        int q2 = tk >> 6;          // 0..19
        int m = q2 % 10, r = q2 / 10;
        const float* pp = &Pls[(size_t)(r * 64 + px) * 104];
        float xs[3];
        #pragma unroll
        for (int c = 0; c < 3; ++c)
            xs[c] = X[((size_t)(b * 3 + c)) * 4096 + (size_t)(y0 + r) * 64 + px];
        float mx = pp[0];
        #pragma unroll
        for (int j = 1; j < 10; ++j) mx = fmaxf(mx, pp[j]);
        float se = 0.f;
        #pragma unroll
        for (int j = 0; j < 10; ++j) se += fexp(pp[j] - mx);
        float lse = mx + flog(se);
        float sum = pp[m] - lse;
        float mean0 = pp[10 + m];
        float mean1 = pp[40 + m];
        float mean2 = pp[70 + m];
        float ls0 = fmaxf(pp[20 + m], -7.f);
        float ls1 = fmaxf(pp[50 + m], -7.f);
        float ls2 = fmaxf(pp[80 + m], -7.f);
        float cf0 = ftanh(pp[30 + m]);
        float cf1 = ftanh(pp[60 + m]);
        float cf2 = ftanh(pp[90 + m]);
        float mu[3], lsv[3];
        mu[0] = mean0;
        mu[1] = mean1 + cf0 * xs[0];
        mu[2] = mean2 + cf1 * xs[0] + cf2 * xs[1];
        lsv[0] = ls0; lsv[1] = ls1; lsv[2] = ls2;
        #pragma unroll
        for (int ci = 0; ci < 3; ++ci) {
            float cent = xs[ci] - mu[ci];
            float inv = fexp(-lsv[ci]);
            float plus_in = inv * (cent + 1.f / 255.f);
            float min_in = inv * (cent - 1.f / 255.f);
            float cdf_delta = fsigmoid(plus_in) - fsigmoid(min_in);
            float log_cdf_plus = plus_in - fsoftplus(plus_in);
            float log_om_cdf = -fsoftplus(min_in);
            float mid = inv * cent;
            float log_pdf_mid = mid - lsv[ci] - 2.f * fsoftplus(mid);
            float lpi = (cdf_delta > 1e-5f) ? flog(fmaxf(cdf_delta, 1e-12f))
                                            : (log_pdf_mid - LOG127P5);
            float lpc = (xs[ci] < -0.999f) ? log_cdf_plus
                       : ((xs[ci] > 0.999f) ? log_om_cdf : lpi);
            sum += lpc;
        }
        lpls[(size_t)(r * 64 + px) * 12 + m] = sum;
    }
    __syncthreads();
    if (t < 128) {
        int px = t & 63, r = t >> 6;
        const float* lp0 = &lpls[(size_t)(r * 64 + px) * 12];
        float mx2 = lp0[0];
        #pragma unroll
        for (int m = 1; m < 10; ++m) mx2 = fmaxf(mx2, lp0[m]);
        float se2 = 0.f;
        #pragma unroll
        for (int m = 0; m < 10; ++m) se2 += fexp(lp0[m] - mx2);
        float lp = mx2 + flog(se2);
        #pragma unroll
        for (int off = 32; off > 0; off >>= 1) lp += __shfl_down(lp, off, 64);
        if ((t & 63) == 0) atomicAdd(&out[b], lp);
    }
}

extern "C" void kernel_launch(void* const* d_in, const int* in_sizes, int n_in,
                              void* d_out, int out_size, void* d_ws, size_t ws_size,
                              hipStream_t stream) {
    const float* samples = (const float*)d_in[0];
    const float* w_in    = (const float*)d_in[1];
    const float* w_blk   = (const float*)d_in[2];
    const float* w_out1  = (const float*)d_in[3];
    const float* w_out2  = (const float*)d_in[4];
    char* ws = (char*)d_ws;
    float* X    = (float*)(ws + X_OFF);
    short* WINP = (short*)(ws + WINP_OFF);
    short* W1P  = (short*)(ws + W1P_OFF);
    short* W2P  = (short*)(ws + W2P_OFF);
    short* WPB  = (short*)(ws + WPB_OFF);
    short* HRA  = (short*)(ws + HRA_OFF);
    short* HRB  = (short*)(ws + HRB_OFF);
    short* MA   = (short*)(ws + MA_OFF);
    short* MB   = (short*)(ws + MB_OFF);
    float* fout = (float*)d_out;

    k_setup<<<2538, 256, 0, stream>>>(samples, w_in, w_blk, w_out1, w_out2,
                                      X, WINP, WPB, W1P, W2P, MA, MB,
                                      fout, out_size);

    k_convin<<<dim3(64, 16), 320, 0, stream>>>(X, WINP, HRA, MA);

    short* a = HRA; short* bq = HRB;
    short* ma = MA; short* mb = MB;
    for (int i = 0; i < 4; i++) {
        k_blk<<<dim3(32, 16), 640, 0, stream>>>(a, ma, bq, mb,
                                                WPB + (size_t)i * 25 * 320 * 32);
        short* tf = a; a = bq; bq = tf;
        short* tm = ma; ma = mb; mb = tm;
    }
    // final fused layer: reads h4 stream (a) + its relu mirror (ma)
    k_blk_head<<<dim3(32, 16), 640, 0, stream>>>(a, ma,
                                                 WPB + (size_t)4 * 25 * 320 * 32,
                                                 W1P, W2P, X, fout);
}